// Round 4
// baseline (214.894 us; speedup 1.0000x reference)
//
#include <hip/hip_runtime.h>
#include <hip/hip_bf16.h>
#include <cstdio>

typedef __bf16 bf16x8 __attribute__((ext_vector_type(8)));
typedef float f32x4 __attribute__((ext_vector_type(4)));

#define BM 128
#define BN 256
#define BK 64

__device__ __forceinline__ unsigned short f2bf(float f) {
  union { float f; unsigned u; } v; v.f = f;
  unsigned u = v.u;
  return (unsigned short)((u + 0x7FFFu + ((u >> 16) & 1u)) >> 16);
}

__device__ __forceinline__ float bf2f(unsigned short s) {
  union { unsigned u; float f; } v; v.u = ((unsigned)s) << 16;
  return v.f;
}

#define GLOAD16(gsrc, ldst) \
  __builtin_amdgcn_global_load_lds((const __attribute__((address_space(1))) void*)(gsrc), \
                                   (__attribute__((address_space(3))) void*)(ldst), 16, 0, 0)

// GEMM-BT, 8-wave 128x256 tile, 4-phase/K-tile schedule (T3+T4+T5).
// C[m][n] = sum_k A[m][k]*B[n][k], A/B row-major bf16, K contiguous.
// Per wave: 64x64 output (4x4 frags), wr=wave>>2 (M half), wc=wave&3 (N quarter).
// LDS: A[2][128][64], B[2][256][64] = 96 KiB. Stage units: A(t)=2 loads/thr,
// B0(t),B1(t)=2 each. Schedule per tile t (buf c=t&1):
//   Ph0 (m01,n01): reads A m01,B n01; stage A(t+1)->c^1   [A(c^1) dead since t-1 Ph2]
//   Ph1 (m01,n23): reads B n23                            [B(c) dead after this]
//   Ph2 (m23,n01): reads A m23; stage B0(t+2)->c          [B(c) dead per Ph1 barrier]
//   Ph3 (m23,n23): no reads;    stage B1(t+2)->c; vmcnt(4); barrier
// vmcnt(4) leaves B01(t+2) in flight; A(t+1)+B01(t+1) confirmed landed (FIFO).
template<int EPI>
__global__ __launch_bounds__(512, 1)
void gemm_bt(const unsigned short* __restrict__ A, const unsigned short* __restrict__ B,
             void* __restrict__ Cv, void* __restrict__ Cv2, const float* __restrict__ bias,
             int K, int ldA, int ldB, int ldC,
             long aBat, long bBat, long cBat,
             int causalSkip, int causalKlim, float scale, int revM)
{
  // T1: bijective XCD-chunked swizzle over the flattened 2D grid (m204 formula)
  const int gx = gridDim.x;
  const int nwg = gx * gridDim.y;
  const int flat = blockIdx.y * gx + blockIdx.x;
  const int qch = nwg >> 3, rch = nwg & 7;
  const int xcd = flat & 7, idx = flat >> 3;
  const int swz = (xcd < rch ? xcd * (qch + 1) : rch * (qch + 1) + (xcd - rch) * qch) + idx;
  const int bx = swz % gx;
  int by = swz / gx;
  if (revM) by = gridDim.y - 1 - by;

  const int m0 = by * BM;
  const int n0 = bx * BN;
  if (causalSkip && n0 > m0 + (BM - 1)) return;   // fully-above-diagonal tiles: skip
  const int bz = blockIdx.z;

  const unsigned short* Ab = A + (long)bz * aBat + (long)m0 * ldA;
  const unsigned short* Bb = B + (long)bz * bBat + (long)n0 * ldB;

  __shared__ short ldsA[2][BM * BK];   // 32 KiB
  __shared__ short ldsB[2][BN * BK];   // 64 KiB

  const int tid = threadIdx.x;
  const int lane = tid & 63;
  const int wave = tid >> 6;
  const int wr = wave >> 2, wc = wave & 3;   // 2M x 4N waves, 64x64 each

  const int Keff = causalKlim ? min(K, m0 + BM) : K;
  const int nk = Keff / BK;                  // >= 2 for all launches here

  const int srow = tid >> 3;   // staging: 8 chunks of 16B per row, 64 rows per load-round
  const int sch = tid & 7;

  const f32x4 fzero = {0.f, 0.f, 0.f, 0.f};
  f32x4 acc[4][4];
#pragma unroll
  for (int i = 0; i < 4; i++)
#pragma unroll
    for (int j = 0; j < 4; j++) acc[i][j] = fzero;

  // fragment LDS offsets (shorts), XOR-swizzled chunk ^= row&7 (rule #21: linear
  // LDS dest for global_load_lds + inverse-swizzled global SOURCE + swizzled READ)
  int aOff[4][2], bOff[4][2];
#pragma unroll
  for (int f = 0; f < 4; f++) {
#pragma unroll
    for (int k = 0; k < 2; k++) {
      int ra = wr * 64 + f * 16 + (lane & 15);
      aOff[f][k] = ra * BK + (((k * 4 + (lane >> 4)) ^ (ra & 7)) * 8);
      int rb = wc * 64 + f * 16 + (lane & 15);
      bOff[f][k] = rb * BK + (((k * 4 + (lane >> 4)) ^ (rb & 7)) * 8);
    }
  }

  auto stageA = [&](int buf, int kt) {
    const unsigned short* Ak = Ab + kt * BK;
#pragma unroll
    for (int L = 0; L < 2; L++) {
      int row = L * 64 + srow;
      int sc = sch ^ (row & 7);           // pre-swizzle the SOURCE chunk
      GLOAD16(Ak + (long)row * ldA + sc * 8, &ldsA[buf][row * BK + sch * 8]);
    }
  };
  auto stageB = [&](int buf, int kt, int h) {
    const unsigned short* Bk = Bb + kt * BK;
#pragma unroll
    for (int L = 0; L < 2; L++) {
      int row = h * 128 + L * 64 + srow;
      int sc = sch ^ (row & 7);
      GLOAD16(Bk + (long)row * ldB + sc * 8, &ldsB[buf][row * BK + sch * 8]);
    }
  };

  // prologue: tile0 (A,B0,B1) + tile1 (B0,B1); wait tile0 landed (4 newer in flight)
  stageA(0, 0); stageB(0, 0, 0); stageB(0, 0, 1);
  if (nk > 1) {
    stageB(1, 1, 0); stageB(1, 1, 1);
    asm volatile("s_waitcnt vmcnt(4)" ::: "memory");
  } else {
    asm volatile("s_waitcnt vmcnt(0)" ::: "memory");
  }
  __builtin_amdgcn_sched_barrier(0);
  __builtin_amdgcn_s_barrier();
  __builtin_amdgcn_sched_barrier(0);

  for (int kt = 0; kt < nk; kt++) {
    const int cur = kt & 1;
    const short* La = ldsA[cur];
    const short* Lb = ldsB[cur];
    bf16x8 a01[2][2], a23[2][2], b01[2][2], b23[2][2];

    // ---------- Phase 0: quadrant (m0-1, n0-1); stage A(t+1)
#pragma unroll
    for (int m = 0; m < 2; m++)
#pragma unroll
      for (int k = 0; k < 2; k++) a01[m][k] = *reinterpret_cast<const bf16x8*>(La + aOff[m][k]);
#pragma unroll
    for (int n = 0; n < 2; n++)
#pragma unroll
      for (int k = 0; k < 2; k++) b01[n][k] = *reinterpret_cast<const bf16x8*>(Lb + bOff[n][k]);
    if (kt + 1 < nk) stageA(cur ^ 1, kt + 1);
    __builtin_amdgcn_s_barrier();
    asm volatile("s_waitcnt lgkmcnt(0)" ::: "memory");
    __builtin_amdgcn_sched_barrier(0);
    __builtin_amdgcn_s_setprio(1);
#pragma unroll
    for (int m = 0; m < 2; m++)
#pragma unroll
      for (int n = 0; n < 2; n++)
#pragma unroll
        for (int k = 0; k < 2; k++)
          acc[m][n] = __builtin_amdgcn_mfma_f32_16x16x32_bf16(a01[m][k], b01[n][k], acc[m][n], 0, 0, 0);
    __builtin_amdgcn_s_setprio(0);
    __builtin_amdgcn_s_barrier();

    // ---------- Phase 1: quadrant (m0-1, n2-3)
#pragma unroll
    for (int n = 0; n < 2; n++)
#pragma unroll
      for (int k = 0; k < 2; k++) b23[n][k] = *reinterpret_cast<const bf16x8*>(Lb + bOff[n + 2][k]);
    __builtin_amdgcn_s_barrier();
    asm volatile("s_waitcnt lgkmcnt(0)" ::: "memory");
    __builtin_amdgcn_sched_barrier(0);
    __builtin_amdgcn_s_setprio(1);
#pragma unroll
    for (int m = 0; m < 2; m++)
#pragma unroll
      for (int n = 0; n < 2; n++)
#pragma unroll
        for (int k = 0; k < 2; k++)
          acc[m][n + 2] = __builtin_amdgcn_mfma_f32_16x16x32_bf16(a01[m][k], b23[n][k], acc[m][n + 2], 0, 0, 0);
    __builtin_amdgcn_s_setprio(0);
    __builtin_amdgcn_s_barrier();   // <- after this, B(cur) is dead (all B reads done)

    // ---------- Phase 2: quadrant (m2-3, n0-1); stage B0(t+2) over dead B(cur)
#pragma unroll
    for (int m = 0; m < 2; m++)
#pragma unroll
      for (int k = 0; k < 2; k++) a23[m][k] = *reinterpret_cast<const bf16x8*>(La + aOff[m + 2][k]);
    if (kt + 2 < nk) stageB(cur, kt + 2, 0);
    __builtin_amdgcn_s_barrier();
    asm volatile("s_waitcnt lgkmcnt(0)" ::: "memory");
    __builtin_amdgcn_sched_barrier(0);
    __builtin_amdgcn_s_setprio(1);
#pragma unroll
    for (int m = 0; m < 2; m++)
#pragma unroll
      for (int n = 0; n < 2; n++)
#pragma unroll
        for (int k = 0; k < 2; k++)
          acc[m + 2][n] = __builtin_amdgcn_mfma_f32_16x16x32_bf16(a23[m][k], b01[n][k], acc[m + 2][n], 0, 0, 0);
    __builtin_amdgcn_s_setprio(0);
    __builtin_amdgcn_s_barrier();   // <- after this, A(cur) is dead

    // ---------- Phase 3: quadrant (m2-3, n2-3); stage B1(t+2); tile-boundary wait
    if (kt + 2 < nk) stageB(cur, kt + 2, 1);
    __builtin_amdgcn_s_barrier();
    __builtin_amdgcn_s_setprio(1);
#pragma unroll
    for (int m = 0; m < 2; m++)
#pragma unroll
      for (int n = 0; n < 2; n++)
#pragma unroll
        for (int k = 0; k < 2; k++)
          acc[m + 2][n + 2] = __builtin_amdgcn_mfma_f32_16x16x32_bf16(a23[m][k], b23[n][k], acc[m + 2][n + 2], 0, 0, 0);
    __builtin_amdgcn_s_setprio(0);
    if (kt + 1 < nk) {
      if (kt + 2 < nk) {
        asm volatile("s_waitcnt vmcnt(4)" ::: "memory");   // tile t+1 landed; B01(t+2) in flight
      } else {
        asm volatile("s_waitcnt vmcnt(0)" ::: "memory");   // tail drain
      }
      __builtin_amdgcn_sched_barrier(0);
      __builtin_amdgcn_s_barrier();
      __builtin_amdgcn_sched_barrier(0);
    }
  }

  // epilogue: C/D map (m89-verified): col=lane&15, row=(lane>>4)*4+reg
  const int rb4 = (lane >> 4) * 4;
  const int cl = lane & 15;
#pragma unroll
  for (int i = 0; i < 4; i++) {
#pragma unroll
    for (int j = 0; j < 4; j++) {
      const int gm = m0 + wr * 64 + i * 16 + rb4;
      const int gn = n0 + wc * 64 + j * 16 + cl;
      if (EPI == 0) {
        unsigned short* C = (unsigned short*)Cv + (long)bz * cBat;
#pragma unroll
        for (int r = 0; r < 4; r++)
          C[(long)(gm + r) * ldC + gn] = f2bf(acc[i][j][r] * scale);
      } else if (EPI == 2) {
        float* C = (float*)Cv;
        const float bb = bias[gn];
#pragma unroll
        for (int r = 0; r < 4; r++)
          C[(long)(gm + r) * ldC + gn] = acc[i][j][r] + bb;
      } else if (EPI == 4) {
        if (gn < 2048) {
          // Q (gn<1024) and K (1024..2047) side by side: QKb[8192][2048]
          unsigned short* C = (unsigned short*)Cv;
#pragma unroll
          for (int r = 0; r < 4; r++)
            C[(long)(gm + r) * ldC + gn] = f2bf(acc[i][j][r]);
        } else {
          // V transposed: Vt[b][d][s], d = gn-2048, b = gm>>11, s = gm&2047
          const int d = gn - 2048;
          const int b = gm >> 11;
          const int sIdx = gm & 2047;
          unsigned short* C = (unsigned short*)Cv2 + (long)b * (2048L * 1024)
                              + (long)d * 2048 + sIdx;
          ushort4 pk;
          pk.x = f2bf(acc[i][j][0]);
          pk.y = f2bf(acc[i][j][1]);
          pk.z = f2bf(acc[i][j][2]);
          pk.w = f2bf(acc[i][j][3]);
          *reinterpret_cast<ushort4*>(C) = pk;
        }
      }
    }
  }
}

// one block per (q row, batch). Causal + padding mask + softmax over bf16 logits.
// Reads/writes only k < kmax = (q & ~127) + 128 — exactly the region the PV GEMM
// (causalKlim, BM=128) consumes; P beyond kmax is never read.
__global__ __launch_bounds__(256)
void softmax_rows(const unsigned short* __restrict__ Sb, const float* __restrict__ maskv,
                  unsigned short* __restrict__ P, int Sdim)
{
  const int q = blockIdx.x;
  const int b = blockIdx.y;
  const int kmax = (q & ~127) + 128;
  const unsigned short* row = Sb + ((long)b * Sdim + q) * Sdim;
  unsigned short* prow = P + ((long)b * Sdim + q) * Sdim;
  const float* mrow = maskv + (long)b * Sdim;
  const int tid = threadIdx.x;
  const float mq = mrow[q];
  const int k0 = tid * 8;
  const bool live = (k0 < kmax);

  float v[8];
  if (live) {
    uint4 raw = *reinterpret_cast<const uint4*>(row + k0);
    const unsigned short* us = reinterpret_cast<const unsigned short*>(&raw);
    float4 ma = *reinterpret_cast<const float4*>(mrow + k0);
    float4 mb = *reinterpret_cast<const float4*>(mrow + k0 + 4);
    float mv[8] = {ma.x, ma.y, ma.z, ma.w, mb.x, mb.y, mb.z, mb.w};
#pragma unroll
    for (int u = 0; u < 8; u++) {
      const int k = k0 + u;
      const bool ok = (k <= q) && (mq * mv[u] == 1.0f);   // square_mask == 1 semantics
      v[u] = ok ? bf2f(us[u]) : -INFINITY;
    }
  } else {
#pragma unroll
    for (int u = 0; u < 8; u++) v[u] = -INFINITY;
  }

  float mx = -INFINITY;
#pragma unroll
  for (int u = 0; u < 8; u++) mx = fmaxf(mx, v[u]);
#pragma unroll
  for (int o = 32; o; o >>= 1) mx = fmaxf(mx, __shfl_xor(mx, o));
  __shared__ float redm[4], reds[4];
  if ((tid & 63) == 0) redm[tid >> 6] = mx;
  __syncthreads();
  mx = fmaxf(fmaxf(redm[0], redm[1]), fmaxf(redm[2], redm[3]));

  float p[8];
  float sm = 0.f;
#pragma unroll
  for (int u = 0; u < 8; u++) {
    p[u] = (v[u] > -INFINITY) ? __expf(v[u] - mx) : 0.f;
    sm += p[u];
  }
#pragma unroll
  for (int o = 32; o; o >>= 1) sm += __shfl_xor(sm, o);
  if ((tid & 63) == 0) reds[tid >> 6] = sm;
  __syncthreads();
  sm = reds[0] + reds[1] + reds[2] + reds[3];
  const float inv = 1.0f / sm;

  if (live) {
    union { unsigned short us[8]; uint4 u4; } pk;
#pragma unroll
    for (int u = 0; u < 8; u++) pk.us[u] = f2bf(p[u] * inv);
    *reinterpret_cast<uint4*>(prow + k0) = pk.u4;
  }
}

// all f32->bf16 casts in ONE dispatch: blocks [0,4096) -> x; [4096,6144) -> weights
__global__ __launch_bounds__(256)
void cast_all(const float* __restrict__ x, const float* __restrict__ w0,
              const float* __restrict__ w1, const float* __restrict__ w2,
              const float* __restrict__ w3,
              unsigned short* __restrict__ xb, unsigned short* __restrict__ dqkv,
              unsigned short* __restrict__ dout)
{
  const int blk = blockIdx.x;
  const float* src;
  unsigned short* dst;
  int i;
  if (blk < 4096) {
    src = x; dst = xb; i = (blk * 256 + threadIdx.x) * 8;
  } else {
    const int w = (blk - 4096) >> 9;          // 0..3  (512 blocks each)
    const int off = (blk - 4096) & 511;
    src = (w == 0) ? w0 : (w == 1) ? w1 : (w == 2) ? w2 : w3;
    dst = (w < 3) ? (dqkv + (long)w * 1024 * 1024) : dout;
    i = (off * 256 + threadIdx.x) * 8;
  }
  float4 a = *reinterpret_cast<const float4*>(src + i);
  float4 b = *reinterpret_cast<const float4*>(src + i + 4);
  union { unsigned short us[8]; uint4 u4; } pk;
  pk.us[0] = f2bf(a.x); pk.us[1] = f2bf(a.y); pk.us[2] = f2bf(a.z); pk.us[3] = f2bf(a.w);
  pk.us[4] = f2bf(b.x); pk.us[5] = f2bf(b.y); pk.us[6] = f2bf(b.z); pk.us[7] = f2bf(b.w);
  *reinterpret_cast<uint4*>(dst + i) = pk.u4;
}

extern "C" void kernel_launch(void* const* d_in, const int* in_sizes, int n_in,
                              void* d_out, int out_size, void* d_ws, size_t ws_size,
                              hipStream_t stream)
{
  const int B = 4, S = 2048, D = 1024;
  const float* x  = (const float*)d_in[0];
  const float* mk = (const float*)d_in[1];
  const float* Wq = (const float*)d_in[2];
  const float* Wk = (const float*)d_in[3];
  const float* Wv = (const float*)d_in[4];
  const float* Wo = (const float*)d_in[5];
  const float* bo = (const float*)d_in[6];
  float* out = (float*)d_out;

  char* ws = (char*)d_ws;
  const long MB = 1024L * 1024L;
  // layout (peak 104 MB with reuse):
  unsigned short* Xbf  = (unsigned short*)(ws + 0);        // 16MB; dead after QKV -> O
  unsigned short* QKb  = (unsigned short*)(ws + 16 * MB);  // 32MB [8192][2048] Q|K; -> P
  unsigned short* Vt   = (unsigned short*)(ws + 48 * MB);  // 16MB V^T per batch [D][S]
  unsigned short* Wqkv = (unsigned short*)(ws + 64 * MB);  // 6MB [3072][1024]
  unsigned short* Wob  = (unsigned short*)(ws + 70 * MB);  // 2MB
  unsigned short* Sbuf = (unsigned short*)(ws + 72 * MB);  // 32MB bf16 logits
  unsigned short* P    = QKb;                              // over dead Q|K
  unsigned short* O    = Xbf;                              // over dead Xbf

  if (ws_size < (size_t)(104 * MB)) {
    fprintf(stderr, "kernel_launch: ws too small (%zu bytes, need 104MB)\n", ws_size);
    return;
  }

  // all casts, one dispatch
  cast_all<<<dim3(4096 + 2048), 256, 0, stream>>>(x, Wq, Wk, Wv, Wo, Xbf, Wqkv, Wob);

  const dim3 blk(512);
  // fused QKV: M=8192, N=3072, K=1024. Q,K -> QKb[8192][2048]; V -> Vt transposed.
  dim3 gQKV(3072 / BN, 8192 / BM, 1);                      // 12 x 64 = 768 = 3 rounds
  gemm_bt<4><<<gQKV, blk, 0, stream>>>(Xbf, Wqkv, QKb, Vt, nullptr,
                                       1024, 1024, 1024, /*ldC*/2048,
                                       0, 0, 0, 0, 0, 1.0f, 0);
  // S = Q K^T / 32 (bf16 out), causal tile-skip, per batch
  dim3 gS(2048 / BN, 2048 / BM, 4);                        // 8 x 16 x 4
  gemm_bt<0><<<gS, blk, 0, stream>>>(QKb, QKb + 1024, Sbuf, nullptr, nullptr,
                                     1024, 2048, 2048, 2048,
                                     (long)S * 2048, (long)S * 2048, (long)S * S,
                                     1, 0, 0.03125f, 0);
  // softmax rows (bf16 in) -> P bf16, causal-limited traffic
  softmax_rows<<<dim3(2048, 4), dim3(256), 0, stream>>>(Sbuf, mk, P, 2048);
  // O = P Vt^T (causal K-limit), per batch
  dim3 gO(1024 / BN, 2048 / BM, 4);                        // 4 x 16 x 4 = 256 = 1 round
  gemm_bt<0><<<gO, blk, 0, stream>>>(P, Vt, O, nullptr, nullptr,
                                     2048, 2048, 2048, 1024,
                                     (long)S * S, (long)D * S, (long)S * D,
                                     0, 1, 1.0f, /*revM*/1);
  // out = O Wo^T + bo
  dim3 gF(1024 / BN, 8192 / BM, 1);                        // 4 x 64 = 256 = 1 round
  gemm_bt<2><<<gF, blk, 0, stream>>>(O, Wob, out, nullptr, bo,
                                     1024, 1024, 1024, 1024,
                                     0, 0, 0, 0, 0, 1.0f, 0);
}

// Round 5
// 189.719 us; speedup vs baseline: 1.1327x; 1.1327x over previous
//
#include <hip/hip_runtime.h>
#include <hip/hip_bf16.h>
#include <cstdio>

typedef __bf16 bf16x8 __attribute__((ext_vector_type(8)));
typedef float f32x4 __attribute__((ext_vector_type(4)));

#define BM 128
#define BN 128
#define BK 64

__device__ __forceinline__ unsigned short f2bf(float f) {
  union { float f; unsigned u; } v; v.f = f;
  unsigned u = v.u;
  return (unsigned short)((u + 0x7FFFu + ((u >> 16) & 1u)) >> 16);
}

__device__ __forceinline__ float bf2f(unsigned short s) {
  union { unsigned u; float f; } v; v.u = ((unsigned)s) << 16;
  return v.f;
}

#define GLOAD16(gsrc, ldst) \
  __builtin_amdgcn_global_load_lds((const __attribute__((address_space(1))) void*)(gsrc), \
                                   (__attribute__((address_space(3))) void*)(ldst), 16, 0, 0)

// ---------------------------------------------------------------------------
// 256x256-tile QKV GEMM, 8 waves, 4-phase/K-tile schedule, counted vmcnt(4).
// C[m][n] = sum_k A[m][k]*B[n][k].  N=3072: gn<2048 -> QK[8192][2048] bf16;
// gn>=2048 -> Vt[b][gn-2048][s] transposed bf16.
// Per wave (wr=wave>>2, wc=wave&3): C rows [wr*128,+128) x cols [wc*64,+64).
// Phase p computes A-quadrant rows [wr*128+p*32,+32) (16 MFMA); B (8 frags)
// read once at Ph0 into regs. Stage ring per K-tile t (buf c=t&1):
//   Ph0: stage A0,A1(t+1)->c^1  [A(c^1) dead since block t-1 end]
//   Ph1: stage B0(t+2)->c       [B(c) dead after Ph0 barrier]
//   Ph2: stage B1(t+2)->c
//   Ph3: boundary vmcnt(4) -> A(t+1),B(t+1) landed; B(t+2) stays in flight.
// ---------------------------------------------------------------------------
__global__ __launch_bounds__(512, 1)
void gemm256_qkv(const unsigned short* __restrict__ A, const unsigned short* __restrict__ B,
                 unsigned short* __restrict__ QK, unsigned short* __restrict__ Vt,
                 int K, int ldA, int ldB)
{
  // T1: bijective XCD-chunked swizzle (m204)
  const int gx = gridDim.x;
  const int nwg = gx * gridDim.y;
  const int flat = blockIdx.y * gx + blockIdx.x;
  const int qch = nwg >> 3, rch = nwg & 7;
  const int xcd = flat & 7, idx = flat >> 3;
  const int swz = (xcd < rch ? xcd * (qch + 1) : rch * (qch + 1) + (xcd - rch) * qch) + idx;
  const int bx = swz % gx;
  const int by = swz / gx;
  const int m0 = by * 256, n0 = bx * 256;

  const unsigned short* Ab = A + (long)m0 * ldA;
  const unsigned short* Bb = B + (long)n0 * ldB;

  __shared__ short ldsA[2][2][128 * 64];   // [dbuf][Mhalf][row*64+k]  64 KiB
  __shared__ short ldsB[2][2][128 * 64];   // [dbuf][Nhalf][row*64+k]  64 KiB

  const int tid = threadIdx.x;
  const int lane = tid & 63;
  const int wave = tid >> 6;
  const int wr = wave >> 2, wc = wave & 3;

  const int nk = K / 64;                   // 16 for K=1024

  const int srow = tid >> 3;               // 64 rows per load-round
  const int sch = tid & 7;
  const int ssc = sch ^ (srow & 7);        // pre-swizzled SOURCE chunk (row&7==srow&7)

  f32x4 acc[8][4];
  const f32x4 fzero = {0.f, 0.f, 0.f, 0.f};
#pragma unroll
  for (int i = 0; i < 8; i++)
#pragma unroll
    for (int j = 0; j < 4; j++) acc[i][j] = fzero;

  // per-lane read constants: row&7 == lane&7 for every fragment row
  const int rowbase = (lane & 15) * 64;
  const int x0 = (((lane >> 4) + 0) ^ (lane & 7)) * 8;   // kslot 0 (shorts)
  const int x1 = (((lane >> 4) + 4) ^ (lane & 7)) * 8;   // kslot 1

  auto stageA = [&](int buf, int kt, int h) {
    const unsigned short* src = Ab + (long)(h * 128) * ldA + kt * 64;
#pragma unroll
    for (int L = 0; L < 2; L++) {
      int row = L * 64 + srow;
      GLOAD16(src + (long)row * ldA + ssc * 8, &ldsA[buf][h][row * 64 + sch * 8]);
    }
  };
  auto stageB = [&](int buf, int kt, int h) {
    const unsigned short* src = Bb + (long)(h * 128) * ldB + kt * 64;
#pragma unroll
    for (int L = 0; L < 2; L++) {
      int row = L * 64 + srow;
      GLOAD16(src + (long)row * ldB + ssc * 8, &ldsB[buf][h][row * 64 + sch * 8]);
    }
  };

  // prologue: K-tile 0 (A+B) -> dbuf0; B(1) -> dbuf1. A(1) staged at block 0 Ph0.
  stageA(0, 0, 0); stageA(0, 0, 1); stageB(0, 0, 0); stageB(0, 0, 1);
  if (nk > 1) {
    stageB(1, 1, 0); stageB(1, 1, 1);
    asm volatile("s_waitcnt vmcnt(4)" ::: "memory");
  } else {
    asm volatile("s_waitcnt vmcnt(0)" ::: "memory");
  }
  __builtin_amdgcn_sched_barrier(0);
  __builtin_amdgcn_s_barrier();
  __builtin_amdgcn_sched_barrier(0);

  for (int kt = 0; kt < nk; kt++) {
    const int c = kt & 1;
    const short* pa = &ldsA[c][wr][rowbase];
    const short* pb = &ldsB[c][wc >> 1][(wc & 1) * 4096 + rowbase];
    bf16x8 b[4][2];
    bf16x8 a[2][2];

    // ---- Phase 0: A quad 0 (fi=0,1) + ALL B; stage A(t+1)->c^1
#pragma unroll
    for (int f = 0; f < 2; f++) {
      a[f][0] = *reinterpret_cast<const bf16x8*>(pa + f * 1024 + x0);
      a[f][1] = *reinterpret_cast<const bf16x8*>(pa + f * 1024 + x1);
    }
#pragma unroll
    for (int f = 0; f < 4; f++) {
      b[f][0] = *reinterpret_cast<const bf16x8*>(pb + f * 1024 + x0);
      b[f][1] = *reinterpret_cast<const bf16x8*>(pb + f * 1024 + x1);
    }
    if (kt + 1 < nk) { stageA(c ^ 1, kt + 1, 0); stageA(c ^ 1, kt + 1, 1); }
    asm volatile("s_waitcnt lgkmcnt(0)" ::: "memory");
    __builtin_amdgcn_sched_barrier(0);
    __builtin_amdgcn_s_setprio(1);
#pragma unroll
    for (int f = 0; f < 2; f++)
#pragma unroll
      for (int j = 0; j < 4; j++)
#pragma unroll
        for (int k = 0; k < 2; k++)
          acc[f][j] = __builtin_amdgcn_mfma_f32_16x16x32_bf16(a[f][k], b[j][k], acc[f][j], 0, 0, 0);
    __builtin_amdgcn_s_setprio(0);
    __builtin_amdgcn_s_barrier();   // B(c) dead; all waves past Ph0 reads

    // ---- Phase 1: A quad 1 (fi=2,3); stage B0(t+2)->c
#pragma unroll
    for (int f = 0; f < 2; f++) {
      a[f][0] = *reinterpret_cast<const bf16x8*>(pa + (f + 2) * 1024 + x0);
      a[f][1] = *reinterpret_cast<const bf16x8*>(pa + (f + 2) * 1024 + x1);
    }
    if (kt + 2 < nk) stageB(c, kt + 2, 0);
    asm volatile("s_waitcnt lgkmcnt(0)" ::: "memory");
    __builtin_amdgcn_sched_barrier(0);
    __builtin_amdgcn_s_setprio(1);
#pragma unroll
    for (int f = 0; f < 2; f++)
#pragma unroll
      for (int j = 0; j < 4; j++)
#pragma unroll
        for (int k = 0; k < 2; k++)
          acc[f + 2][j] = __builtin_amdgcn_mfma_f32_16x16x32_bf16(a[f][k], b[j][k], acc[f + 2][j], 0, 0, 0);
    __builtin_amdgcn_s_setprio(0);
    __builtin_amdgcn_s_barrier();

    // ---- Phase 2: A quad 2 (fi=4,5); stage B1(t+2)->c
#pragma unroll
    for (int f = 0; f < 2; f++) {
      a[f][0] = *reinterpret_cast<const bf16x8*>(pa + (f + 4) * 1024 + x0);
      a[f][1] = *reinterpret_cast<const bf16x8*>(pa + (f + 4) * 1024 + x1);
    }
    if (kt + 2 < nk) stageB(c, kt + 2, 1);
    asm volatile("s_waitcnt lgkmcnt(0)" ::: "memory");
    __builtin_amdgcn_sched_barrier(0);
    __builtin_amdgcn_s_setprio(1);
#pragma unroll
    for (int f = 0; f < 2; f++)
#pragma unroll
      for (int j = 0; j < 4; j++)
#pragma unroll
        for (int k = 0; k < 2; k++)
          acc[f + 4][j] = __builtin_amdgcn_mfma_f32_16x16x32_bf16(a[f][k], b[j][k], acc[f + 4][j], 0, 0, 0);
    __builtin_amdgcn_s_setprio(0);
    __builtin_amdgcn_s_barrier();

    // ---- Phase 3: A quad 3 (fi=6,7); boundary vmcnt + barrier
#pragma unroll
    for (int f = 0; f < 2; f++) {
      a[f][0] = *reinterpret_cast<const bf16x8*>(pa + (f + 6) * 1024 + x0);
      a[f][1] = *reinterpret_cast<const bf16x8*>(pa + (f + 6) * 1024 + x1);
    }
    asm volatile("s_waitcnt lgkmcnt(0)" ::: "memory");
    __builtin_amdgcn_sched_barrier(0);
    __builtin_amdgcn_s_setprio(1);
#pragma unroll
    for (int f = 0; f < 2; f++)
#pragma unroll
      for (int j = 0; j < 4; j++)
#pragma unroll
        for (int k = 0; k < 2; k++)
          acc[f + 6][j] = __builtin_amdgcn_mfma_f32_16x16x32_bf16(a[f][k], b[j][k], acc[f + 6][j], 0, 0, 0);
    __builtin_amdgcn_s_setprio(0);
    if (kt + 1 < nk) {
      if (kt + 2 < nk) asm volatile("s_waitcnt vmcnt(4)" ::: "memory");
      else             asm volatile("s_waitcnt vmcnt(0)" ::: "memory");
      __builtin_amdgcn_sched_barrier(0);
    }
    __builtin_amdgcn_s_barrier();
    __builtin_amdgcn_sched_barrier(0);
  }

  // epilogue: C/D map col=lane&15, row=(lane>>4)*4+reg (m89-verified)
  const int rb4 = (lane >> 4) * 4;
  const int cl = lane & 15;
#pragma unroll
  for (int fi = 0; fi < 8; fi++) {
#pragma unroll
    for (int fj = 0; fj < 4; fj++) {
      const int gm = m0 + wr * 128 + fi * 16 + rb4;
      const int gn = n0 + wc * 64 + fj * 16 + cl;
      if (gn < 2048) {
#pragma unroll
        for (int r = 0; r < 4; r++)
          QK[(long)(gm + r) * 2048 + gn] = f2bf(acc[fi][fj][r]);
      } else {
        const int d = gn - 2048;
        const int bb = gm >> 11;
        const int sIdx = gm & 2047;
        unsigned short* C = Vt + (long)bb * (2048L * 1024) + (long)d * 2048 + sIdx;
        ushort4 pk;
        pk.x = f2bf(acc[fi][fj][0]);
        pk.y = f2bf(acc[fi][fj][1]);
        pk.z = f2bf(acc[fi][fj][2]);
        pk.w = f2bf(acc[fi][fj][3]);
        *reinterpret_cast<ushort4*>(C) = pk;
      }
    }
  }
}

// ---------------------------------------------------------------------------
// Proven R3 128x128 GEMM-BT (counted vmcnt(8), 2 blocks/CU).
// EPI 0: bf16 store (scale);  EPI 2: fp32 store + bias.
// ---------------------------------------------------------------------------
template<int EPI>
__global__ __launch_bounds__(256, 2)
void gemm_bt(const unsigned short* __restrict__ A, const unsigned short* __restrict__ B,
             void* __restrict__ Cv, const float* __restrict__ bias,
             int K, int ldA, int ldB, int ldC,
             long aBat, long bBat, long cBat,
             int causalSkip, int causalKlim, float scale, int revM)
{
  const int gx = gridDim.x;
  const int nwg = gx * gridDim.y;
  const int flat = blockIdx.y * gx + blockIdx.x;
  const int qch = nwg >> 3, rch = nwg & 7;
  const int xcd = flat & 7, idx = flat >> 3;
  const int swz = (xcd < rch ? xcd * (qch + 1) : rch * (qch + 1) + (xcd - rch) * qch) + idx;
  const int bx = swz % gx;
  int by = swz / gx;
  if (revM) by = gridDim.y - 1 - by;

  const int m0 = by * BM;
  const int n0 = bx * BN;
  if (causalSkip && n0 > m0) return;
  const int bz = blockIdx.z;

  const unsigned short* Ab = A + (long)bz * aBat + (long)m0 * ldA;
  const unsigned short* Bb = B + (long)bz * bBat + (long)n0 * ldB;

  __shared__ short lds[2][2][BM * BK];

  const int tid = threadIdx.x;
  const int lane = tid & 63;
  const int wave = tid >> 6;
  const int wr = wave >> 1, wc = wave & 1;

  const int Keff = causalKlim ? min(K, m0 + BM) : K;
  const int nk = Keff / BK;

  const int srow = tid >> 3;
  const int sch = tid & 7;

  const f32x4 fzero = {0.f, 0.f, 0.f, 0.f};
  f32x4 acc[4][4];
#pragma unroll
  for (int i = 0; i < 4; i++)
#pragma unroll
    for (int j = 0; j < 4; j++) acc[i][j] = fzero;

  int aOff[4][2], bOff[4][2];
#pragma unroll
  for (int i = 0; i < 4; i++) {
#pragma unroll
    for (int s = 0; s < 2; s++) {
      int ra = wr * 64 + i * 16 + (lane & 15);
      aOff[i][s] = ra * BK + (((s * 4 + (lane >> 4)) ^ (ra & 7)) * 8);
      int rb = wc * 64 + i * 16 + (lane & 15);
      bOff[i][s] = rb * BK + (((s * 4 + (lane >> 4)) ^ (rb & 7)) * 8);
    }
  }

  auto stage = [&](int buf, int kt) {
    const unsigned short* Ak = Ab + kt * BK;
    const unsigned short* Bk = Bb + kt * BK;
#pragma unroll
    for (int r = 0; r < 4; r++) {
      int row = r * 32 + srow;
      int sc = sch ^ (row & 7);
      GLOAD16(Ak + (long)row * ldA + sc * 8, &lds[buf][0][(r * 32 + wave * 8) * BK]);
    }
#pragma unroll
    for (int r = 0; r < 4; r++) {
      int row = r * 32 + srow;
      int sc = sch ^ (row & 7);
      GLOAD16(Bk + (long)row * ldB + sc * 8, &lds[buf][1][(r * 32 + wave * 8) * BK]);
    }
  };

  stage(0, 0);
  stage(1, 1);
  asm volatile("s_waitcnt vmcnt(8)" ::: "memory");
  __builtin_amdgcn_sched_barrier(0);
  __builtin_amdgcn_s_barrier();

  int cur = 0;
  for (int kt = 0; kt < nk; kt++) {
    const short* La = lds[cur][0];
    const short* Lb = lds[cur][1];
    bf16x8 av[2][4], bv[2][4];
#pragma unroll
    for (int s = 0; s < 2; s++) {
#pragma unroll
      for (int i = 0; i < 4; i++) {
        av[s][i] = *reinterpret_cast<const bf16x8*>(La + aOff[i][s]);
        bv[s][i] = *reinterpret_cast<const bf16x8*>(Lb + bOff[i][s]);
      }
    }
    asm volatile("s_waitcnt lgkmcnt(0)" ::: "memory");
    __builtin_amdgcn_sched_barrier(0);
    __builtin_amdgcn_s_barrier();
    __builtin_amdgcn_sched_barrier(0);

    if (kt + 2 < nk) {
      stage(cur, kt + 2);
      asm volatile("s_waitcnt vmcnt(8)" ::: "memory");
    } else if (kt + 1 < nk) {
      asm volatile("s_waitcnt vmcnt(0)" ::: "memory");
    }
    if (kt + 1 < nk) {
      __builtin_amdgcn_s_barrier();
      __builtin_amdgcn_sched_barrier(0);
    }

    __builtin_amdgcn_s_setprio(1);
#pragma unroll
    for (int s = 0; s < 2; s++)
#pragma unroll
      for (int i = 0; i < 4; i++)
#pragma unroll
        for (int j = 0; j < 4; j++)
          acc[i][j] = __builtin_amdgcn_mfma_f32_16x16x32_bf16(av[s][i], bv[s][j], acc[i][j], 0, 0, 0);
    __builtin_amdgcn_s_setprio(0);
    __builtin_amdgcn_sched_barrier(0);
    cur ^= 1;
  }

  const int rb4 = (lane >> 4) * 4;
  const int cl = lane & 15;
#pragma unroll
  for (int i = 0; i < 4; i++) {
#pragma unroll
    for (int j = 0; j < 4; j++) {
      const int gm = m0 + wr * 64 + i * 16 + rb4;
      const int gn = n0 + wc * 64 + j * 16 + cl;
      if (EPI == 0) {
        unsigned short* C = (unsigned short*)Cv + (long)bz * cBat;
#pragma unroll
        for (int r = 0; r < 4; r++)
          C[(long)(gm + r) * ldC + gn] = f2bf(acc[i][j][r] * scale);
      } else {
        float* C = (float*)Cv;
        const float bb = bias[gn];
#pragma unroll
        for (int r = 0; r < 4; r++)
          C[(long)(gm + r) * ldC + gn] = acc[i][j][r] + bb;
      }
    }
  }
}

// one block per (q row, batch). Causal + padding mask + softmax over bf16 logits.
__global__ __launch_bounds__(256)
void softmax_rows(const unsigned short* __restrict__ Sb, const float* __restrict__ maskv,
                  unsigned short* __restrict__ P, int Sdim)
{
  const int q = blockIdx.x;
  const int b = blockIdx.y;
  const int kmax = (q & ~127) + 128;
  const unsigned short* row = Sb + ((long)b * Sdim + q) * Sdim;
  unsigned short* prow = P + ((long)b * Sdim + q) * Sdim;
  const float* mrow = maskv + (long)b * Sdim;
  const int tid = threadIdx.x;
  const float mq = mrow[q];
  const int k0 = tid * 8;
  const bool live = (k0 < kmax);

  float v[8];
  if (live) {
    uint4 raw = *reinterpret_cast<const uint4*>(row + k0);
    const unsigned short* us = reinterpret_cast<const unsigned short*>(&raw);
    float4 ma = *reinterpret_cast<const float4*>(mrow + k0);
    float4 mb = *reinterpret_cast<const float4*>(mrow + k0 + 4);
    float mv[8] = {ma.x, ma.y, ma.z, ma.w, mb.x, mb.y, mb.z, mb.w};
#pragma unroll
    for (int u = 0; u < 8; u++) {
      const int k = k0 + u;
      const bool ok = (k <= q) && (mq * mv[u] == 1.0f);
      v[u] = ok ? bf2f(us[u]) : -INFINITY;
    }
  } else {
#pragma unroll
    for (int u = 0; u < 8; u++) v[u] = -INFINITY;
  }

  float mx = -INFINITY;
#pragma unroll
  for (int u = 0; u < 8; u++) mx = fmaxf(mx, v[u]);
#pragma unroll
  for (int o = 32; o; o >>= 1) mx = fmaxf(mx, __shfl_xor(mx, o));
  __shared__ float redm[4], reds[4];
  if ((tid & 63) == 0) redm[tid >> 6] = mx;
  __syncthreads();
  mx = fmaxf(fmaxf(redm[0], redm[1]), fmaxf(redm[2], redm[3]));

  float p[8];
  float sm = 0.f;
#pragma unroll
  for (int u = 0; u < 8; u++) {
    p[u] = (v[u] > -INFINITY) ? __expf(v[u] - mx) : 0.f;
    sm += p[u];
  }
#pragma unroll
  for (int o = 32; o; o >>= 1) sm += __shfl_xor(sm, o);
  if ((tid & 63) == 0) reds[tid >> 6] = sm;
  __syncthreads();
  sm = reds[0] + reds[1] + reds[2] + reds[3];
  const float inv = 1.0f / sm;

  if (live) {
    union { unsigned short us[8]; uint4 u4; } pk;
#pragma unroll
    for (int u = 0; u < 8; u++) pk.us[u] = f2bf(p[u] * inv);
    *reinterpret_cast<uint4*>(prow + k0) = pk.u4;
  }
}

// all f32->bf16 casts in ONE dispatch: blocks [0,4096) -> x; [4096,6144) -> weights
__global__ __launch_bounds__(256)
void cast_all(const float* __restrict__ x, const float* __restrict__ w0,
              const float* __restrict__ w1, const float* __restrict__ w2,
              const float* __restrict__ w3,
              unsigned short* __restrict__ xb, unsigned short* __restrict__ dqkv,
              unsigned short* __restrict__ dout)
{
  const int blk = blockIdx.x;
  const float* src;
  unsigned short* dst;
  int i;
  if (blk < 4096) {
    src = x; dst = xb; i = (blk * 256 + threadIdx.x) * 8;
  } else {
    const int w = (blk - 4096) >> 9;
    const int off = (blk - 4096) & 511;
    src = (w == 0) ? w0 : (w == 1) ? w1 : (w == 2) ? w2 : w3;
    dst = (w < 3) ? (dqkv + (long)w * 1024 * 1024) : dout;
    i = (off * 256 + threadIdx.x) * 8;
  }
  float4 a = *reinterpret_cast<const float4*>(src + i);
  float4 b = *reinterpret_cast<const float4*>(src + i + 4);
  union { unsigned short us[8]; uint4 u4; } pk;
  pk.us[0] = f2bf(a.x); pk.us[1] = f2bf(a.y); pk.us[2] = f2bf(a.z); pk.us[3] = f2bf(a.w);
  pk.us[4] = f2bf(b.x); pk.us[5] = f2bf(b.y); pk.us[6] = f2bf(b.z); pk.us[7] = f2bf(b.w);
  *reinterpret_cast<uint4*>(dst + i) = pk.u4;
}

extern "C" void kernel_launch(void* const* d_in, const int* in_sizes, int n_in,
                              void* d_out, int out_size, void* d_ws, size_t ws_size,
                              hipStream_t stream)
{
  const int B = 4, S = 2048, D = 1024;
  const float* x  = (const float*)d_in[0];
  const float* mk = (const float*)d_in[1];
  const float* Wq = (const float*)d_in[2];
  const float* Wk = (const float*)d_in[3];
  const float* Wv = (const float*)d_in[4];
  const float* Wo = (const float*)d_in[5];
  const float* bo = (const float*)d_in[6];
  float* out = (float*)d_out;

  char* ws = (char*)d_ws;
  const long MB = 1024L * 1024L;
  unsigned short* Xbf  = (unsigned short*)(ws + 0);        // 16MB; dead after QKV -> O
  unsigned short* QKb  = (unsigned short*)(ws + 16 * MB);  // 32MB [8192][2048] Q|K; -> P
  unsigned short* Vt   = (unsigned short*)(ws + 48 * MB);  // 16MB V^T per batch [D][S]
  unsigned short* Wqkv = (unsigned short*)(ws + 64 * MB);  // 6MB [3072][1024]
  unsigned short* Wob  = (unsigned short*)(ws + 70 * MB);  // 2MB
  unsigned short* Sbuf = (unsigned short*)(ws + 72 * MB);  // 32MB bf16 logits
  unsigned short* P    = QKb;
  unsigned short* O    = Xbf;

  if (ws_size < (size_t)(104 * MB)) {
    fprintf(stderr, "kernel_launch: ws too small (%zu bytes, need 104MB)\n", ws_size);
    return;
  }

  cast_all<<<dim3(4096 + 2048), 256, 0, stream>>>(x, Wq, Wk, Wv, Wo, Xbf, Wqkv, Wob);

  // fused QKV: M=8192, N=3072, K=1024 — 256^2 4-phase kernel (12x32=384 blocks)
  gemm256_qkv<<<dim3(12, 32), dim3(512), 0, stream>>>(Xbf, Wqkv, QKb, Vt, 1024, 1024, 1024);

  const dim3 blk(256);
  // S = Q K^T / 32 (bf16 out), causal tile-skip, per batch
  dim3 gS(2048 / BN, 2048 / BM, 4);
  gemm_bt<0><<<gS, blk, 0, stream>>>(QKb, QKb + 1024, Sbuf, nullptr,
                                     1024, 2048, 2048, 2048,
                                     (long)S * 2048, (long)S * 2048, (long)S * S,
                                     1, 0, 0.03125f, 0);
  // softmax rows (bf16 in) -> P bf16, causal-limited traffic
  softmax_rows<<<dim3(2048, 4), blk, 0, stream>>>(Sbuf, mk, P, 2048);
  // O = P Vt^T (causal K-limit, heavy tiles first), per batch
  dim3 gO(1024 / BN, 2048 / BM, 4);
  gemm_bt<0><<<gO, blk, 0, stream>>>(P, Vt, O, nullptr,
                                     2048, 2048, 2048, 1024,
                                     (long)S * S, (long)D * S, (long)S * D,
                                     0, 1, 1.0f, 1);
  // out = O Wo^T + bo
  dim3 gF(1024 / BN, 8192 / BM, 1);
  gemm_bt<2><<<gF, blk, 0, stream>>>(O, Wob, out, bo,
                                     1024, 1024, 1024, 1024,
                                     0, 0, 0, 0, 0, 1.0f, 0);
}

// Round 6
// 182.965 us; speedup vs baseline: 1.1745x; 1.0369x over previous
//
#include <hip/hip_runtime.h>
#include <hip/hip_bf16.h>
#include <cstdio>

typedef __bf16 bf16x8 __attribute__((ext_vector_type(8)));
typedef float f32x4 __attribute__((ext_vector_type(4)));

#define BM 128
#define BN 128
#define BK 64

__device__ __forceinline__ unsigned short f2bf(float f) {
  union { float f; unsigned u; } v; v.f = f;
  unsigned u = v.u;
  return (unsigned short)((u + 0x7FFFu + ((u >> 16) & 1u)) >> 16);
}

__device__ __forceinline__ float bf2f(unsigned short s) {
  union { unsigned u; float f; } v; v.u = ((unsigned)s) << 16;
  return v.f;
}

#define GLOAD16(gsrc, ldst) \
  __builtin_amdgcn_global_load_lds((const __attribute__((address_space(1))) void*)(gsrc), \
                                   (__attribute__((address_space(3))) void*)(ldst), 16, 0, 0)

// ---------------------------------------------------------------------------
// m97-faithful single-buffered 128x128 GEMM-BT, 32 KiB LDS, 3 blocks/CU.
// Per K-step: stage(kt) -> syncthreads -> ds_read frags + MFMA -> syncthreads.
// The barrier drain (vmcnt0+lgkm0) is hidden by 3-block/CU wave overlap (m114).
// C[m][n] = sum_k A[m][k]*B[n][k], A/B row-major bf16, K contiguous.
// EPI 0: bf16 store (scale)
// EPI 2: fp32 store + bias
// EPI 4: QKV split epilogue: gn<1024 -> Qb[gm][gn]; gn<2048 -> Kb[gm][gn-1024];
//        gn>=2048 -> Vt[b][gn-2048][s] transposed (Cv3)
// ---------------------------------------------------------------------------
template<int EPI>
__global__ __launch_bounds__(256, 3)
void gemm_bt(const unsigned short* __restrict__ A, const unsigned short* __restrict__ B,
             void* __restrict__ Cv, void* __restrict__ Cv2, void* __restrict__ Cv3,
             const float* __restrict__ bias,
             int K, int ldA, int ldB, int ldC,
             long aBat, long bBat, long cBat,
             int causalSkip, int causalKlim, float scale, int revM)
{
  // T1: bijective XCD-chunked swizzle (m204)
  const int gx = gridDim.x;
  const int nwg = gx * gridDim.y;
  const int flat = blockIdx.y * gx + blockIdx.x;
  const int qch = nwg >> 3, rch = nwg & 7;
  const int xcd = flat & 7, idx = flat >> 3;
  const int swz = (xcd < rch ? xcd * (qch + 1) : rch * (qch + 1) + (xcd - rch) * qch) + idx;
  const int bx = swz % gx;
  int by = swz / gx;
  if (revM) by = gridDim.y - 1 - by;

  const int m0 = by * BM;
  const int n0 = bx * BN;
  if (causalSkip && n0 > m0) return;   // strictly-upper causal tiles: skip
  const int bz = blockIdx.z;

  const unsigned short* Ab = A + (long)bz * aBat + (long)m0 * ldA;
  const unsigned short* Bb = B + (long)bz * bBat + (long)n0 * ldB;

  __shared__ short lds[2][BM * BK];   // [A/B], 32 KiB single-buffered

  const int tid = threadIdx.x;
  const int lane = tid & 63;
  const int wave = tid >> 6;
  const int wr = wave >> 1, wc = wave & 1;   // wave -> 64x64 quadrant

  const int Keff = causalKlim ? min(K, m0 + BM) : K;
  const int nk = Keff / BK;

  const int srow = tid >> 3;   // staging: 8 lanes per row (8 chunks of 16B)
  const int sch = tid & 7;

  const f32x4 fzero = {0.f, 0.f, 0.f, 0.f};
  f32x4 acc[4][4];
#pragma unroll
  for (int i = 0; i < 4; i++)
#pragma unroll
    for (int j = 0; j < 4; j++) acc[i][j] = fzero;

  // fragment LDS offsets (shorts), XOR-swizzled: chunk ^= row&7 (rule #21:
  // linear LDS dest for global_load_lds + inverse-swizzled global SOURCE + swizzled READ)
  int aOff[4][2], bOff[4][2];
#pragma unroll
  for (int i = 0; i < 4; i++) {
#pragma unroll
    for (int s = 0; s < 2; s++) {
      int ra = wr * 64 + i * 16 + (lane & 15);
      aOff[i][s] = ra * BK + (((s * 4 + (lane >> 4)) ^ (ra & 7)) * 8);
      int rb = wc * 64 + i * 16 + (lane & 15);
      bOff[i][s] = rb * BK + (((s * 4 + (lane >> 4)) ^ (rb & 7)) * 8);
    }
  }

  for (int kt = 0; kt < nk; kt++) {
    // stage tile kt into LDS (8 global_load_lds per thread)
    const unsigned short* Ak = Ab + kt * BK;
    const unsigned short* Bk = Bb + kt * BK;
#pragma unroll
    for (int r = 0; r < 4; r++) {
      int row = r * 32 + srow;
      int sc = sch ^ (row & 7);           // pre-swizzle the SOURCE chunk
      GLOAD16(Ak + (long)row * ldA + sc * 8, &lds[0][(r * 32 + wave * 8) * BK]);
    }
#pragma unroll
    for (int r = 0; r < 4; r++) {
      int row = r * 32 + srow;
      int sc = sch ^ (row & 7);
      GLOAD16(Bk + (long)row * ldB + sc * 8, &lds[1][(r * 32 + wave * 8) * BK]);
    }
    __syncthreads();   // drains vmcnt (staging complete)

#pragma unroll
    for (int s = 0; s < 2; s++) {
      bf16x8 av[4], bv[4];
#pragma unroll
      for (int i = 0; i < 4; i++) av[i] = *reinterpret_cast<const bf16x8*>(lds[0] + aOff[i][s]);
#pragma unroll
      for (int j = 0; j < 4; j++) bv[j] = *reinterpret_cast<const bf16x8*>(lds[1] + bOff[j][s]);
#pragma unroll
      for (int i = 0; i < 4; i++)
#pragma unroll
        for (int j = 0; j < 4; j++)
          acc[i][j] = __builtin_amdgcn_mfma_f32_16x16x32_bf16(av[i], bv[j], acc[i][j], 0, 0, 0);
    }
    __syncthreads();   // all reads done before next stage overwrites
  }

  // epilogue: C/D map (m89-verified): col=lane&15, row=(lane>>4)*4+reg
  const int rb4 = (lane >> 4) * 4;
  const int cl = lane & 15;
#pragma unroll
  for (int i = 0; i < 4; i++) {
#pragma unroll
    for (int j = 0; j < 4; j++) {
      const int gm = m0 + wr * 64 + i * 16 + rb4;
      const int gn = n0 + wc * 64 + j * 16 + cl;
      if (EPI == 0) {
        unsigned short* C = (unsigned short*)Cv + (long)bz * cBat;
#pragma unroll
        for (int r = 0; r < 4; r++)
          C[(long)(gm + r) * ldC + gn] = f2bf(acc[i][j][r] * scale);
      } else if (EPI == 2) {
        float* C = (float*)Cv;
        const float bb = bias[gn];
#pragma unroll
        for (int r = 0; r < 4; r++)
          C[(long)(gm + r) * ldC + gn] = acc[i][j][r] + bb;
      } else if (EPI == 4) {
        if (gn < 1024) {
          unsigned short* C = (unsigned short*)Cv;        // Qb [8192][1024]
#pragma unroll
          for (int r = 0; r < 4; r++)
            C[(long)(gm + r) * 1024 + gn] = f2bf(acc[i][j][r]);
        } else if (gn < 2048) {
          unsigned short* C = (unsigned short*)Cv2;       // Kb [8192][1024]
#pragma unroll
          for (int r = 0; r < 4; r++)
            C[(long)(gm + r) * 1024 + (gn - 1024)] = f2bf(acc[i][j][r]);
        } else {
          // V transposed: Vt[b][d][s], d = gn-2048, b = gm>>11, s = gm&2047
          const int d = gn - 2048;
          const int b = gm >> 11;
          const int sIdx = gm & 2047;
          unsigned short* C = (unsigned short*)Cv3 + (long)b * (2048L * 1024)
                              + (long)d * 2048 + sIdx;
          ushort4 pk;
          pk.x = f2bf(acc[i][j][0]);
          pk.y = f2bf(acc[i][j][1]);
          pk.z = f2bf(acc[i][j][2]);
          pk.w = f2bf(acc[i][j][3]);
          *reinterpret_cast<ushort4*>(C) = pk;
        }
      }
    }
  }
}

// one block per (q row, batch). Causal + padding mask + softmax over bf16 logits.
// Reads/writes only k < kmax = (q & ~127) + 128 — exactly the region the PV GEMM
// (causalKlim, BM=128) consumes; P beyond kmax is never read.
__global__ __launch_bounds__(256)
void softmax_rows(const unsigned short* __restrict__ Sb, const float* __restrict__ maskv,
                  unsigned short* __restrict__ P, int Sdim)
{
  const int q = blockIdx.x;
  const int b = blockIdx.y;
  const int kmax = (q & ~127) + 128;
  const unsigned short* row = Sb + ((long)b * Sdim + q) * Sdim;
  unsigned short* prow = P + ((long)b * Sdim + q) * Sdim;
  const float* mrow = maskv + (long)b * Sdim;
  const int tid = threadIdx.x;
  const float mq = mrow[q];
  const int k0 = tid * 8;
  const bool live = (k0 < kmax);

  float v[8];
  if (live) {
    uint4 raw = *reinterpret_cast<const uint4*>(row + k0);
    const unsigned short* us = reinterpret_cast<const unsigned short*>(&raw);
    float4 ma = *reinterpret_cast<const float4*>(mrow + k0);
    float4 mb = *reinterpret_cast<const float4*>(mrow + k0 + 4);
    float mv[8] = {ma.x, ma.y, ma.z, ma.w, mb.x, mb.y, mb.z, mb.w};
#pragma unroll
    for (int u = 0; u < 8; u++) {
      const int k = k0 + u;
      const bool ok = (k <= q) && (mq * mv[u] == 1.0f);   // square_mask == 1 semantics
      v[u] = ok ? bf2f(us[u]) : -INFINITY;
    }
  } else {
#pragma unroll
    for (int u = 0; u < 8; u++) v[u] = -INFINITY;
  }

  float mx = -INFINITY;
#pragma unroll
  for (int u = 0; u < 8; u++) mx = fmaxf(mx, v[u]);
#pragma unroll
  for (int o = 32; o; o >>= 1) mx = fmaxf(mx, __shfl_xor(mx, o));
  __shared__ float redm[4], reds[4];
  if ((tid & 63) == 0) redm[tid >> 6] = mx;
  __syncthreads();
  mx = fmaxf(fmaxf(redm[0], redm[1]), fmaxf(redm[2], redm[3]));

  float p[8];
  float sm = 0.f;
#pragma unroll
  for (int u = 0; u < 8; u++) {
    p[u] = (v[u] > -INFINITY) ? __expf(v[u] - mx) : 0.f;
    sm += p[u];
  }
#pragma unroll
  for (int o = 32; o; o >>= 1) sm += __shfl_xor(sm, o);
  if ((tid & 63) == 0) reds[tid >> 6] = sm;
  __syncthreads();
  sm = reds[0] + reds[1] + reds[2] + reds[3];
  const float inv = 1.0f / sm;

  if (live) {
    union { unsigned short us[8]; uint4 u4; } pk;
#pragma unroll
    for (int u = 0; u < 8; u++) pk.us[u] = f2bf(p[u] * inv);
    *reinterpret_cast<uint4*>(prow + k0) = pk.u4;
  }
}

// all f32->bf16 casts in ONE dispatch: blocks [0,4096) -> x; [4096,6144) -> weights
__global__ __launch_bounds__(256)
void cast_all(const float* __restrict__ x, const float* __restrict__ w0,
              const float* __restrict__ w1, const float* __restrict__ w2,
              const float* __restrict__ w3,
              unsigned short* __restrict__ xb, unsigned short* __restrict__ dqkv,
              unsigned short* __restrict__ dout)
{
  const int blk = blockIdx.x;
  const float* src;
  unsigned short* dst;
  int i;
  if (blk < 4096) {
    src = x; dst = xb; i = (blk * 256 + threadIdx.x) * 8;
  } else {
    const int w = (blk - 4096) >> 9;
    const int off = (blk - 4096) & 511;
    src = (w == 0) ? w0 : (w == 1) ? w1 : (w == 2) ? w2 : w3;
    dst = (w < 3) ? (dqkv + (long)w * 1024 * 1024) : dout;
    i = (off * 256 + threadIdx.x) * 8;
  }
  float4 a = *reinterpret_cast<const float4*>(src + i);
  float4 b = *reinterpret_cast<const float4*>(src + i + 4);
  union { unsigned short us[8]; uint4 u4; } pk;
  pk.us[0] = f2bf(a.x); pk.us[1] = f2bf(a.y); pk.us[2] = f2bf(a.z); pk.us[3] = f2bf(a.w);
  pk.us[4] = f2bf(b.x); pk.us[5] = f2bf(b.y); pk.us[6] = f2bf(b.z); pk.us[7] = f2bf(b.w);
  *reinterpret_cast<uint4*>(dst + i) = pk.u4;
}

extern "C" void kernel_launch(void* const* d_in, const int* in_sizes, int n_in,
                              void* d_out, int out_size, void* d_ws, size_t ws_size,
                              hipStream_t stream)
{
  const int B = 4, S = 2048, D = 1024;
  const float* x  = (const float*)d_in[0];
  const float* mk = (const float*)d_in[1];
  const float* Wq = (const float*)d_in[2];
  const float* Wk = (const float*)d_in[3];
  const float* Wv = (const float*)d_in[4];
  const float* Wo = (const float*)d_in[5];
  const float* bo = (const float*)d_in[6];
  float* out = (float*)d_out;

  char* ws = (char*)d_ws;
  const long MB = 1024L * 1024L;
  unsigned short* Xbf  = (unsigned short*)(ws + 0);        // 16MB; dead after QKV -> O
  unsigned short* Qb   = (unsigned short*)(ws + 16 * MB);  // 16MB [8192][1024]; -> P
  unsigned short* Kb   = (unsigned short*)(ws + 32 * MB);  // 16MB [8192][1024]; -> P
  unsigned short* Vt   = (unsigned short*)(ws + 48 * MB);  // 16MB V^T per batch [D][S]
  unsigned short* Wqkv = (unsigned short*)(ws + 64 * MB);  // 6MB [3072][1024]
  unsigned short* Wob  = (unsigned short*)(ws + 70 * MB);  // 2MB
  unsigned short* Sbuf = (unsigned short*)(ws + 72 * MB);  // 32MB bf16 logits
  unsigned short* P    = Qb;                               // 32MB over dead Q+K
  unsigned short* O    = Xbf;                              // over dead Xbf

  if (ws_size < (size_t)(104 * MB)) {
    fprintf(stderr, "kernel_launch: ws too small (%zu bytes, need 104MB)\n", ws_size);
    return;
  }

  cast_all<<<dim3(4096 + 2048), 256, 0, stream>>>(x, Wq, Wk, Wv, Wo, Xbf, Wqkv, Wob);

  const dim3 blk(256);
  // fused QKV: M=8192, N=3072, K=1024 -> Qb, Kb, Vt.  1536 blocks = 2 rounds @3/CU.
  dim3 gQKV(3072 / BN, 8192 / BM, 1);
  gemm_bt<4><<<gQKV, blk, 0, stream>>>(Xbf, Wqkv, Qb, Kb, Vt, nullptr,
                                       1024, 1024, 1024, 0,
                                       0, 0, 0, 0, 0, 1.0f, 0);
  // S = Q K^T / 32 (bf16 out), causal tile-skip, per batch
  dim3 gS(2048 / BN, 2048 / BM, 4);
  gemm_bt<0><<<gS, blk, 0, stream>>>(Qb, Kb, Sbuf, nullptr, nullptr, nullptr,
                                     1024, 1024, 1024, 2048,
                                     (long)S * 1024, (long)S * 1024, (long)S * S,
                                     1, 0, 0.03125f, 0);
  // softmax rows (bf16 in) -> P bf16, causal-limited traffic
  softmax_rows<<<dim3(2048, 4), blk, 0, stream>>>(Sbuf, mk, P, 2048);
  // O = P Vt^T (causal K-limit, heavy tiles first), per batch
  dim3 gO(1024 / BN, 2048 / BM, 4);
  gemm_bt<0><<<gO, blk, 0, stream>>>(P, Vt, O, nullptr, nullptr, nullptr,
                                     2048, 2048, 2048, 1024,
                                     (long)S * S, (long)D * S, (long)S * D,
                                     0, 1, 1.0f, 1);
  // out = O Wo^T + bo
  dim3 gF(1024 / BN, 8192 / BM, 1);
  gemm_bt<2><<<gF, blk, 0, stream>>>(O, Wob, out, nullptr, nullptr, bo,
                                     1024, 1024, 1024, 1024,
                                     0, 0, 0, 0, 0, 1.0f, 0);
}

// Round 7
// 175.410 us; speedup vs baseline: 1.2251x; 1.0431x over previous
//
#include <hip/hip_runtime.h>
#include <hip/hip_bf16.h>
#include <cstdio>

typedef __bf16 bf16x8 __attribute__((ext_vector_type(8)));
typedef float f32x4 __attribute__((ext_vector_type(4)));

#define BM 128
#define BN 128
#define BK 64

__device__ __forceinline__ unsigned short f2bf(float f) {
  union { float f; unsigned u; } v; v.f = f;
  unsigned u = v.u;
  return (unsigned short)((u + 0x7FFFu + ((u >> 16) & 1u)) >> 16);
}

__device__ __forceinline__ float bf2f(unsigned short s) {
  union { unsigned u; float f; } v; v.u = ((unsigned)s) << 16;
  return v.f;
}

#define GLOAD16(gsrc, ldst) \
  __builtin_amdgcn_global_load_lds((const __attribute__((address_space(1))) void*)(gsrc), \
                                   (__attribute__((address_space(3))) void*)(ldst), 16, 0, 0)

// ---------------------------------------------------------------------------
// Single-buffered m97-style 128x128 GEMM-BT, 32 KiB LDS, 3 blocks/CU.
// For dispatches with >=2 blocks/CU (inter-block overlap hides barrier drain).
// EPI 0: bf16 store (scale)
// EPI 4: QKV split epilogue: gn<1024 -> Qb; gn<2048 -> Kb; gn>=2048 -> Vt transposed
// ---------------------------------------------------------------------------
template<int EPI>
__global__ __launch_bounds__(256, 3)
void gemm_sb(const unsigned short* __restrict__ A, const unsigned short* __restrict__ B,
             void* __restrict__ Cv, void* __restrict__ Cv2, void* __restrict__ Cv3,
             int K, int ldA, int ldB, int ldC,
             long aBat, long bBat, long cBat,
             int causalSkip, float scale)
{
  // T1: bijective XCD-chunked swizzle (m204)
  const int gx = gridDim.x;
  const int nwg = gx * gridDim.y;
  const int flat = blockIdx.y * gx + blockIdx.x;
  const int qch = nwg >> 3, rch = nwg & 7;
  const int xcd = flat & 7, idx = flat >> 3;
  const int swz = (xcd < rch ? xcd * (qch + 1) : rch * (qch + 1) + (xcd - rch) * qch) + idx;
  const int bx = swz % gx;
  const int by = swz / gx;

  const int m0 = by * BM;
  const int n0 = bx * BN;
  if (causalSkip && n0 > m0) return;   // strictly-upper causal tiles: skip
  const int bz = blockIdx.z;

  const unsigned short* Ab = A + (long)bz * aBat + (long)m0 * ldA;
  const unsigned short* Bb = B + (long)bz * bBat + (long)n0 * ldB;

  __shared__ short lds[2][BM * BK];   // [A/B], 32 KiB single-buffered

  const int tid = threadIdx.x;
  const int lane = tid & 63;
  const int wave = tid >> 6;
  const int wr = wave >> 1, wc = wave & 1;

  const int nk = K / BK;

  const int srow = tid >> 3;
  const int sch = tid & 7;

  const f32x4 fzero = {0.f, 0.f, 0.f, 0.f};
  f32x4 acc[4][4];
#pragma unroll
  for (int i = 0; i < 4; i++)
#pragma unroll
    for (int j = 0; j < 4; j++) acc[i][j] = fzero;

  int aOff[4][2], bOff[4][2];
#pragma unroll
  for (int i = 0; i < 4; i++) {
#pragma unroll
    for (int s = 0; s < 2; s++) {
      int ra = wr * 64 + i * 16 + (lane & 15);
      aOff[i][s] = ra * BK + (((s * 4 + (lane >> 4)) ^ (ra & 7)) * 8);
      int rb = wc * 64 + i * 16 + (lane & 15);
      bOff[i][s] = rb * BK + (((s * 4 + (lane >> 4)) ^ (rb & 7)) * 8);
    }
  }

  for (int kt = 0; kt < nk; kt++) {
    const unsigned short* Ak = Ab + kt * BK;
    const unsigned short* Bk = Bb + kt * BK;
#pragma unroll
    for (int r = 0; r < 4; r++) {
      int row = r * 32 + srow;
      int sc = sch ^ (row & 7);           // pre-swizzle the SOURCE chunk
      GLOAD16(Ak + (long)row * ldA + sc * 8, &lds[0][(r * 32 + wave * 8) * BK]);
    }
#pragma unroll
    for (int r = 0; r < 4; r++) {
      int row = r * 32 + srow;
      int sc = sch ^ (row & 7);
      GLOAD16(Bk + (long)row * ldB + sc * 8, &lds[1][(r * 32 + wave * 8) * BK]);
    }
    __syncthreads();

#pragma unroll
    for (int s = 0; s < 2; s++) {
      bf16x8 av[4], bv[4];
#pragma unroll
      for (int i = 0; i < 4; i++) av[i] = *reinterpret_cast<const bf16x8*>(lds[0] + aOff[i][s]);
#pragma unroll
      for (int j = 0; j < 4; j++) bv[j] = *reinterpret_cast<const bf16x8*>(lds[1] + bOff[j][s]);
#pragma unroll
      for (int i = 0; i < 4; i++)
#pragma unroll
        for (int j = 0; j < 4; j++)
          acc[i][j] = __builtin_amdgcn_mfma_f32_16x16x32_bf16(av[i], bv[j], acc[i][j], 0, 0, 0);
    }
    __syncthreads();
  }

  // epilogue: C/D map (m89-verified): col=lane&15, row=(lane>>4)*4+reg
  const int rb4 = (lane >> 4) * 4;
  const int cl = lane & 15;
#pragma unroll
  for (int i = 0; i < 4; i++) {
#pragma unroll
    for (int j = 0; j < 4; j++) {
      const int gm = m0 + wr * 64 + i * 16 + rb4;
      const int gn = n0 + wc * 64 + j * 16 + cl;
      if (EPI == 0) {
        unsigned short* C = (unsigned short*)Cv + (long)bz * cBat;
#pragma unroll
        for (int r = 0; r < 4; r++)
          C[(long)(gm + r) * ldC + gn] = f2bf(acc[i][j][r] * scale);
      } else {
        if (gn < 1024) {
          unsigned short* C = (unsigned short*)Cv;        // Qb [8192][1024]
#pragma unroll
          for (int r = 0; r < 4; r++)
            C[(long)(gm + r) * 1024 + gn] = f2bf(acc[i][j][r]);
        } else if (gn < 2048) {
          unsigned short* C = (unsigned short*)Cv2;       // Kb [8192][1024]
#pragma unroll
          for (int r = 0; r < 4; r++)
            C[(long)(gm + r) * 1024 + (gn - 1024)] = f2bf(acc[i][j][r]);
        } else {
          const int d = gn - 2048;
          const int b = gm >> 11;
          const int sIdx = gm & 2047;
          unsigned short* C = (unsigned short*)Cv3 + (long)b * (2048L * 1024)
                              + (long)d * 2048 + sIdx;
          ushort4 pk;
          pk.x = f2bf(acc[i][j][0]);
          pk.y = f2bf(acc[i][j][1]);
          pk.z = f2bf(acc[i][j][2]);
          pk.w = f2bf(acc[i][j][3]);
          *reinterpret_cast<ushort4*>(C) = pk;
        }
      }
    }
  }
}

// ---------------------------------------------------------------------------
// Double-buffered counted-vmcnt 128x128 GEMM-BT (R3-verified), 2-deep prefetch.
// For 1-block/CU dispatches (PV, F): intra-block pipeline hides barrier drain.
// EPI 0: bf16 store (scale);  EPI 2: fp32 store + bias.
// ---------------------------------------------------------------------------
template<int EPI>
__global__ __launch_bounds__(256, 2)
void gemm_db(const unsigned short* __restrict__ A, const unsigned short* __restrict__ B,
             void* __restrict__ Cv, const float* __restrict__ bias,
             int K, int ldA, int ldB, int ldC,
             long aBat, long bBat, long cBat,
             int causalKlim, float scale, int revM)
{
  const int gx = gridDim.x;
  const int nwg = gx * gridDim.y;
  const int flat = blockIdx.y * gx + blockIdx.x;
  const int qch = nwg >> 3, rch = nwg & 7;
  const int xcd = flat & 7, idx = flat >> 3;
  const int swz = (xcd < rch ? xcd * (qch + 1) : rch * (qch + 1) + (xcd - rch) * qch) + idx;
  const int bx = swz % gx;
  int by = swz / gx;
  if (revM) by = gridDim.y - 1 - by;

  const int m0 = by * BM;
  const int n0 = bx * BN;
  const int bz = blockIdx.z;

  const unsigned short* Ab = A + (long)bz * aBat + (long)m0 * ldA;
  const unsigned short* Bb = B + (long)bz * bBat + (long)n0 * ldB;

  __shared__ short lds[2][2][BM * BK];

  const int tid = threadIdx.x;
  const int lane = tid & 63;
  const int wave = tid >> 6;
  const int wr = wave >> 1, wc = wave & 1;

  const int Keff = causalKlim ? min(K, m0 + BM) : K;
  const int nk = Keff / BK;                  // >= 2 for all launches here

  const int srow = tid >> 3;
  const int sch = tid & 7;

  const f32x4 fzero = {0.f, 0.f, 0.f, 0.f};
  f32x4 acc[4][4];
#pragma unroll
  for (int i = 0; i < 4; i++)
#pragma unroll
    for (int j = 0; j < 4; j++) acc[i][j] = fzero;

  int aOff[4][2], bOff[4][2];
#pragma unroll
  for (int i = 0; i < 4; i++) {
#pragma unroll
    for (int s = 0; s < 2; s++) {
      int ra = wr * 64 + i * 16 + (lane & 15);
      aOff[i][s] = ra * BK + (((s * 4 + (lane >> 4)) ^ (ra & 7)) * 8);
      int rb = wc * 64 + i * 16 + (lane & 15);
      bOff[i][s] = rb * BK + (((s * 4 + (lane >> 4)) ^ (rb & 7)) * 8);
    }
  }

  auto stage = [&](int buf, int kt) {
    const unsigned short* Ak = Ab + kt * BK;
    const unsigned short* Bk = Bb + kt * BK;
#pragma unroll
    for (int r = 0; r < 4; r++) {
      int row = r * 32 + srow;
      int sc = sch ^ (row & 7);
      GLOAD16(Ak + (long)row * ldA + sc * 8, &lds[buf][0][(r * 32 + wave * 8) * BK]);
    }
#pragma unroll
    for (int r = 0; r < 4; r++) {
      int row = r * 32 + srow;
      int sc = sch ^ (row & 7);
      GLOAD16(Bk + (long)row * ldB + sc * 8, &lds[buf][1][(r * 32 + wave * 8) * BK]);
    }
  };

  stage(0, 0);
  stage(1, 1);
  asm volatile("s_waitcnt vmcnt(8)" ::: "memory");
  __builtin_amdgcn_sched_barrier(0);
  __builtin_amdgcn_s_barrier();

  int cur = 0;
  for (int kt = 0; kt < nk; kt++) {
    const short* La = lds[cur][0];
    const short* Lb = lds[cur][1];
    bf16x8 av[2][4], bv[2][4];
#pragma unroll
    for (int s = 0; s < 2; s++) {
#pragma unroll
      for (int i = 0; i < 4; i++) {
        av[s][i] = *reinterpret_cast<const bf16x8*>(La + aOff[i][s]);
        bv[s][i] = *reinterpret_cast<const bf16x8*>(Lb + bOff[i][s]);
      }
    }
    asm volatile("s_waitcnt lgkmcnt(0)" ::: "memory");
    __builtin_amdgcn_sched_barrier(0);
    __builtin_amdgcn_s_barrier();            // all waves done reading buf[cur]
    __builtin_amdgcn_sched_barrier(0);

    if (kt + 2 < nk) {
      stage(cur, kt + 2);                    // overwrite dead buffer
      asm volatile("s_waitcnt vmcnt(8)" ::: "memory");   // tile kt+1 landed (FIFO)
    } else if (kt + 1 < nk) {
      asm volatile("s_waitcnt vmcnt(0)" ::: "memory");
    }
    if (kt + 1 < nk) {
      __builtin_amdgcn_s_barrier();
      __builtin_amdgcn_sched_barrier(0);
    }

    __builtin_amdgcn_s_setprio(1);
#pragma unroll
    for (int s = 0; s < 2; s++)
#pragma unroll
      for (int i = 0; i < 4; i++)
#pragma unroll
        for (int j = 0; j < 4; j++)
          acc[i][j] = __builtin_amdgcn_mfma_f32_16x16x32_bf16(av[s][i], bv[s][j], acc[i][j], 0, 0, 0);
    __builtin_amdgcn_s_setprio(0);
    __builtin_amdgcn_sched_barrier(0);
    cur ^= 1;
  }

  const int rb4 = (lane >> 4) * 4;
  const int cl = lane & 15;
#pragma unroll
  for (int i = 0; i < 4; i++) {
#pragma unroll
    for (int j = 0; j < 4; j++) {
      const int gm = m0 + wr * 64 + i * 16 + rb4;
      const int gn = n0 + wc * 64 + j * 16 + cl;
      if (EPI == 0) {
        unsigned short* C = (unsigned short*)Cv + (long)bz * cBat;
#pragma unroll
        for (int r = 0; r < 4; r++)
          C[(long)(gm + r) * ldC + gn] = f2bf(acc[i][j][r] * scale);
      } else {
        float* C = (float*)Cv;
        const float bb = bias[gn];
#pragma unroll
        for (int r = 0; r < 4; r++)
          C[(long)(gm + r) * ldC + gn] = acc[i][j][r] + bb;
      }
    }
  }
}

// one WAVE per (q row); 4 rows per block; shfl-only reduction (no __syncthreads).
// Causal + padding mask over bf16 logits; reads/writes only k < kmax.
__global__ __launch_bounds__(256)
void softmax_rows(const unsigned short* __restrict__ Sb, const float* __restrict__ maskv,
                  unsigned short* __restrict__ P, int Sdim)
{
  const int wv = threadIdx.x >> 6;
  const int lane = threadIdx.x & 63;
  const int q = blockIdx.x * 4 + wv;
  const int b = blockIdx.y;
  const int kmax = (q & ~127) + 128;
  const unsigned short* row = Sb + ((long)b * Sdim + q) * Sdim;
  unsigned short* prow = P + ((long)b * Sdim + q) * Sdim;
  const float* mrow = maskv + (long)b * Sdim;
  const float mq = mrow[q];

  float v[4][8];
  float mx = -INFINITY;
#pragma unroll
  for (int c = 0; c < 4; c++) {
    const int k0 = c * 512 + lane * 8;
    if (c * 512 < kmax) {
      uint4 raw = *reinterpret_cast<const uint4*>(row + k0);
      const unsigned short* us = reinterpret_cast<const unsigned short*>(&raw);
      float4 ma = *reinterpret_cast<const float4*>(mrow + k0);
      float4 mb = *reinterpret_cast<const float4*>(mrow + k0 + 4);
      float mv[8] = {ma.x, ma.y, ma.z, ma.w, mb.x, mb.y, mb.z, mb.w};
#pragma unroll
      for (int u = 0; u < 8; u++) {
        const int k = k0 + u;
        const bool ok = (k <= q) && (mq * mv[u] == 1.0f);   // square_mask == 1 semantics
        v[c][u] = ok ? bf2f(us[u]) : -INFINITY;
        mx = fmaxf(mx, v[c][u]);
      }
    } else {
#pragma unroll
      for (int u = 0; u < 8; u++) v[c][u] = -INFINITY;
    }
  }
#pragma unroll
  for (int o = 32; o; o >>= 1) mx = fmaxf(mx, __shfl_xor(mx, o));

  float sm = 0.f;
#pragma unroll
  for (int c = 0; c < 4; c++)
#pragma unroll
    for (int u = 0; u < 8; u++) {
      v[c][u] = (v[c][u] > -INFINITY) ? __expf(v[c][u] - mx) : 0.f;
      sm += v[c][u];
    }
#pragma unroll
  for (int o = 32; o; o >>= 1) sm += __shfl_xor(sm, o);
  const float inv = 1.0f / sm;

#pragma unroll
  for (int c = 0; c < 4; c++) {
    if (c * 512 < kmax) {
      union { unsigned short us[8]; uint4 u4; } pk;
#pragma unroll
      for (int u = 0; u < 8; u++) pk.us[u] = f2bf(v[c][u] * inv);
      *reinterpret_cast<uint4*>(prow + c * 512 + lane * 8) = pk.u4;
    }
  }
}

// all f32->bf16 casts in ONE dispatch: blocks [0,4096) -> x; [4096,6144) -> weights
__global__ __launch_bounds__(256)
void cast_all(const float* __restrict__ x, const float* __restrict__ w0,
              const float* __restrict__ w1, const float* __restrict__ w2,
              const float* __restrict__ w3,
              unsigned short* __restrict__ xb, unsigned short* __restrict__ dqkv,
              unsigned short* __restrict__ dout)
{
  const int blk = blockIdx.x;
  const float* src;
  unsigned short* dst;
  int i;
  if (blk < 4096) {
    src = x; dst = xb; i = (blk * 256 + threadIdx.x) * 8;
  } else {
    const int w = (blk - 4096) >> 9;
    const int off = (blk - 4096) & 511;
    src = (w == 0) ? w0 : (w == 1) ? w1 : (w == 2) ? w2 : w3;
    dst = (w < 3) ? (dqkv + (long)w * 1024 * 1024) : dout;
    i = (off * 256 + threadIdx.x) * 8;
  }
  float4 a = *reinterpret_cast<const float4*>(src + i);
  float4 b = *reinterpret_cast<const float4*>(src + i + 4);
  union { unsigned short us[8]; uint4 u4; } pk;
  pk.us[0] = f2bf(a.x); pk.us[1] = f2bf(a.y); pk.us[2] = f2bf(a.z); pk.us[3] = f2bf(a.w);
  pk.us[4] = f2bf(b.x); pk.us[5] = f2bf(b.y); pk.us[6] = f2bf(b.z); pk.us[7] = f2bf(b.w);
  *reinterpret_cast<uint4*>(dst + i) = pk.u4;
}

extern "C" void kernel_launch(void* const* d_in, const int* in_sizes, int n_in,
                              void* d_out, int out_size, void* d_ws, size_t ws_size,
                              hipStream_t stream)
{
  const int B = 4, S = 2048, D = 1024;
  const float* x  = (const float*)d_in[0];
  const float* mk = (const float*)d_in[1];
  const float* Wq = (const float*)d_in[2];
  const float* Wk = (const float*)d_in[3];
  const float* Wv = (const float*)d_in[4];
  const float* Wo = (const float*)d_in[5];
  const float* bo = (const float*)d_in[6];
  float* out = (float*)d_out;

  char* ws = (char*)d_ws;
  const long MB = 1024L * 1024L;
  unsigned short* Xbf  = (unsigned short*)(ws + 0);        // 16MB; dead after QKV -> O
  unsigned short* Qb   = (unsigned short*)(ws + 16 * MB);  // 16MB [8192][1024]; -> P
  unsigned short* Kb   = (unsigned short*)(ws + 32 * MB);  // 16MB [8192][1024]; -> P
  unsigned short* Vt   = (unsigned short*)(ws + 48 * MB);  // 16MB V^T per batch [D][S]
  unsigned short* Wqkv = (unsigned short*)(ws + 64 * MB);  // 6MB [3072][1024]
  unsigned short* Wob  = (unsigned short*)(ws + 70 * MB);  // 2MB
  unsigned short* Sbuf = (unsigned short*)(ws + 72 * MB);  // 32MB bf16 logits
  unsigned short* P    = Qb;                               // 32MB over dead Q+K
  unsigned short* O    = Xbf;                              // over dead Xbf

  if (ws_size < (size_t)(104 * MB)) {
    fprintf(stderr, "kernel_launch: ws too small (%zu bytes, need 104MB)\n", ws_size);
    return;
  }

  cast_all<<<dim3(4096 + 2048), 256, 0, stream>>>(x, Wq, Wk, Wv, Wo, Xbf, Wqkv, Wob);

  const dim3 blk(256);
  // fused QKV: M=8192, N=3072, K=1024 -> Qb, Kb, Vt.  1536 blocks = 2 rounds @3/CU.
  dim3 gQKV(3072 / BN, 8192 / BM, 1);
  gemm_sb<4><<<gQKV, blk, 0, stream>>>(Xbf, Wqkv, Qb, Kb, Vt,
                                       1024, 1024, 1024, 0,
                                       0, 0, 0, 0, 1.0f);
  // S = Q K^T / 32 (bf16 out), causal tile-skip, per batch (544 live blocks)
  dim3 gS(2048 / BN, 2048 / BM, 4);
  gemm_sb<0><<<gS, blk, 0, stream>>>(Qb, Kb, Sbuf, nullptr, nullptr,
                                     1024, 1024, 1024, 2048,
                                     (long)S * 1024, (long)S * 1024, (long)S * S,
                                     1, 0.03125f);
  // softmax: one wave per row, 4 rows/block, no __syncthreads
  softmax_rows<<<dim3(512, 4), blk, 0, stream>>>(Sbuf, mk, P, 2048);
  // O = P Vt^T (causal K-limit, heavy tiles first): 256 blocks = 1/CU -> dbuf kernel
  dim3 gO(1024 / BN, 2048 / BM, 4);
  gemm_db<0><<<gO, blk, 0, stream>>>(P, Vt, O, nullptr,
                                     2048, 2048, 2048, 1024,
                                     (long)S * S, (long)D * S, (long)S * D,
                                     1, 1.0f, 1);
  // out = O Wo^T + bo: 256 blocks = 1/CU -> dbuf kernel
  dim3 gF(1024 / BN, 8192 / BM, 1);
  gemm_db<2><<<gF, blk, 0, stream>>>(O, Wob, out, bo,
                                     1024, 1024, 1024, 1024,
                                     0, 0, 0, 0, 1.0f, 0);
}

// Round 8
// 167.840 us; speedup vs baseline: 1.2803x; 1.0451x over previous
//
#include <hip/hip_runtime.h>
#include <hip/hip_bf16.h>
#include <cstdio>

typedef __bf16 bf16x8 __attribute__((ext_vector_type(8)));
typedef float f32x4 __attribute__((ext_vector_type(4)));

#define BM 128
#define BN 128
#define BK 64

__device__ __forceinline__ unsigned short f2bf(float f) {
  union { float f; unsigned u; } v; v.f = f;
  unsigned u = v.u;
  return (unsigned short)((u + 0x7FFFu + ((u >> 16) & 1u)) >> 16);
}

__device__ __forceinline__ float bf2f(unsigned short s) {
  union { unsigned u; float f; } v; v.u = ((unsigned)s) << 16;
  return v.f;
}

#define GLOAD16(gsrc, ldst) \
  __builtin_amdgcn_global_load_lds((const __attribute__((address_space(1))) void*)(gsrc), \
                                   (__attribute__((address_space(3))) void*)(ldst), 16, 0, 0)

// ---------------------------------------------------------------------------
// Single-buffered m97-style 128x128 GEMM-BT, 32 KiB LDS, 3 blocks/CU.
// EPI 0: bf16 store (scale)
// EPI 4: QKV split epilogue: gn<1024 -> Qb; gn<2048 -> Kb; gn>=2048 -> VWt transposed
// ---------------------------------------------------------------------------
template<int EPI>
__global__ __launch_bounds__(256, 3)
void gemm_sb(const unsigned short* __restrict__ A, const unsigned short* __restrict__ B,
             void* __restrict__ Cv, void* __restrict__ Cv2, void* __restrict__ Cv3,
             int K, int ldA, int ldB, int ldC,
             long aBat, long bBat, long cBat,
             int causalSkip, float scale)
{
  // T1: bijective XCD-chunked swizzle (m204)
  const int gx = gridDim.x;
  const int nwg = gx * gridDim.y;
  const int flat = blockIdx.y * gx + blockIdx.x;
  const int qch = nwg >> 3, rch = nwg & 7;
  const int xcd = flat & 7, idx = flat >> 3;
  const int swz = (xcd < rch ? xcd * (qch + 1) : rch * (qch + 1) + (xcd - rch) * qch) + idx;
  const int bx = swz % gx;
  const int by = swz / gx;

  const int m0 = by * BM;
  const int n0 = bx * BN;
  if (causalSkip && n0 > m0) return;
  const int bz = blockIdx.z;

  const unsigned short* Ab = A + (long)bz * aBat + (long)m0 * ldA;
  const unsigned short* Bb = B + (long)bz * bBat + (long)n0 * ldB;

  __shared__ short lds[2][BM * BK];   // [A/B], 32 KiB single-buffered

  const int tid = threadIdx.x;
  const int lane = tid & 63;
  const int wave = tid >> 6;
  const int wr = wave >> 1, wc = wave & 1;

  const int nk = K / BK;

  const int srow = tid >> 3;
  const int sch = tid & 7;

  const f32x4 fzero = {0.f, 0.f, 0.f, 0.f};
  f32x4 acc[4][4];
#pragma unroll
  for (int i = 0; i < 4; i++)
#pragma unroll
    for (int j = 0; j < 4; j++) acc[i][j] = fzero;

  int aOff[4][2], bOff[4][2];
#pragma unroll
  for (int i = 0; i < 4; i++) {
#pragma unroll
    for (int s = 0; s < 2; s++) {
      int ra = wr * 64 + i * 16 + (lane & 15);
      aOff[i][s] = ra * BK + (((s * 4 + (lane >> 4)) ^ (ra & 7)) * 8);
      int rb = wc * 64 + i * 16 + (lane & 15);
      bOff[i][s] = rb * BK + (((s * 4 + (lane >> 4)) ^ (rb & 7)) * 8);
    }
  }

  for (int kt = 0; kt < nk; kt++) {
    const unsigned short* Ak = Ab + kt * BK;
    const unsigned short* Bk = Bb + kt * BK;
#pragma unroll
    for (int r = 0; r < 4; r++) {
      int row = r * 32 + srow;
      int sc = sch ^ (row & 7);
      GLOAD16(Ak + (long)row * ldA + sc * 8, &lds[0][(r * 32 + wave * 8) * BK]);
    }
#pragma unroll
    for (int r = 0; r < 4; r++) {
      int row = r * 32 + srow;
      int sc = sch ^ (row & 7);
      GLOAD16(Bk + (long)row * ldB + sc * 8, &lds[1][(r * 32 + wave * 8) * BK]);
    }
    __syncthreads();

#pragma unroll
    for (int s = 0; s < 2; s++) {
      bf16x8 av[4], bv[4];
#pragma unroll
      for (int i = 0; i < 4; i++) av[i] = *reinterpret_cast<const bf16x8*>(lds[0] + aOff[i][s]);
#pragma unroll
      for (int j = 0; j < 4; j++) bv[j] = *reinterpret_cast<const bf16x8*>(lds[1] + bOff[j][s]);
#pragma unroll
      for (int i = 0; i < 4; i++)
#pragma unroll
        for (int j = 0; j < 4; j++)
          acc[i][j] = __builtin_amdgcn_mfma_f32_16x16x32_bf16(av[i], bv[j], acc[i][j], 0, 0, 0);
    }
    __syncthreads();
  }

  const int rb4 = (lane >> 4) * 4;
  const int cl = lane & 15;
#pragma unroll
  for (int i = 0; i < 4; i++) {
#pragma unroll
    for (int j = 0; j < 4; j++) {
      const int gm = m0 + wr * 64 + i * 16 + rb4;
      const int gn = n0 + wc * 64 + j * 16 + cl;
      if (EPI == 0) {
        unsigned short* C = (unsigned short*)Cv + (long)bz * cBat;
#pragma unroll
        for (int r = 0; r < 4; r++)
          C[(long)(gm + r) * ldC + gn] = f2bf(acc[i][j][r] * scale);
      } else {
        if (gn < 1024) {
          unsigned short* C = (unsigned short*)Cv;        // Qb [8192][1024]
#pragma unroll
          for (int r = 0; r < 4; r++)
            C[(long)(gm + r) * 1024 + gn] = f2bf(acc[i][j][r]);
        } else if (gn < 2048) {
          unsigned short* C = (unsigned short*)Cv2;       // Kb [8192][1024]
#pragma unroll
          for (int r = 0; r < 4; r++)
            C[(long)(gm + r) * 1024 + (gn - 1024)] = f2bf(acc[i][j][r]);
        } else {
          // VW transposed: VWt[b][d][s], d = gn-2048, b = gm>>11, s = gm&2047
          const int d = gn - 2048;
          const int b = gm >> 11;
          const int sIdx = gm & 2047;
          unsigned short* C = (unsigned short*)Cv3 + (long)b * (2048L * 1024)
                              + (long)d * 2048 + sIdx;
          ushort4 pk;
          pk.x = f2bf(acc[i][j][0]);
          pk.y = f2bf(acc[i][j][1]);
          pk.z = f2bf(acc[i][j][2]);
          pk.w = f2bf(acc[i][j][3]);
          *reinterpret_cast<ushort4*>(C) = pk;
        }
      }
    }
  }
}

// ---------------------------------------------------------------------------
// Double-buffered counted-vmcnt 128x128 GEMM-BT (R3-verified), 2-deep prefetch.
// EPI 0: bf16 store (scale);  EPI 2: fp32 store + bias + batch offset.
// ---------------------------------------------------------------------------
template<int EPI>
__global__ __launch_bounds__(256, 2)
void gemm_db(const unsigned short* __restrict__ A, const unsigned short* __restrict__ B,
             void* __restrict__ Cv, const float* __restrict__ bias,
             int K, int ldA, int ldB, int ldC,
             long aBat, long bBat, long cBat,
             int causalKlim, float scale, int revM)
{
  const int gx = gridDim.x;
  const int nwg = gx * gridDim.y;
  const int flat = blockIdx.y * gx + blockIdx.x;
  const int qch = nwg >> 3, rch = nwg & 7;
  const int xcd = flat & 7, idx = flat >> 3;
  const int swz = (xcd < rch ? xcd * (qch + 1) : rch * (qch + 1) + (xcd - rch) * qch) + idx;
  const int bx = swz % gx;
  int by = swz / gx;
  if (revM) by = gridDim.y - 1 - by;

  const int m0 = by * BM;
  const int n0 = bx * BN;
  const int bz = blockIdx.z;

  const unsigned short* Ab = A + (long)bz * aBat + (long)m0 * ldA;
  const unsigned short* Bb = B + (long)bz * bBat + (long)n0 * ldB;

  __shared__ short lds[2][2][BM * BK];

  const int tid = threadIdx.x;
  const int lane = tid & 63;
  const int wave = tid >> 6;
  const int wr = wave >> 1, wc = wave & 1;

  const int Keff = causalKlim ? min(K, m0 + BM) : K;
  const int nk = Keff / BK;

  const int srow = tid >> 3;
  const int sch = tid & 7;

  const f32x4 fzero = {0.f, 0.f, 0.f, 0.f};
  f32x4 acc[4][4];
#pragma unroll
  for (int i = 0; i < 4; i++)
#pragma unroll
    for (int j = 0; j < 4; j++) acc[i][j] = fzero;

  int aOff[4][2], bOff[4][2];
#pragma unroll
  for (int i = 0; i < 4; i++) {
#pragma unroll
    for (int s = 0; s < 2; s++) {
      int ra = wr * 64 + i * 16 + (lane & 15);
      aOff[i][s] = ra * BK + (((s * 4 + (lane >> 4)) ^ (ra & 7)) * 8);
      int rb = wc * 64 + i * 16 + (lane & 15);
      bOff[i][s] = rb * BK + (((s * 4 + (lane >> 4)) ^ (rb & 7)) * 8);
    }
  }

  auto stage = [&](int buf, int kt) {
    const unsigned short* Ak = Ab + kt * BK;
    const unsigned short* Bk = Bb + kt * BK;
#pragma unroll
    for (int r = 0; r < 4; r++) {
      int row = r * 32 + srow;
      int sc = sch ^ (row & 7);
      GLOAD16(Ak + (long)row * ldA + sc * 8, &lds[buf][0][(r * 32 + wave * 8) * BK]);
    }
#pragma unroll
    for (int r = 0; r < 4; r++) {
      int row = r * 32 + srow;
      int sc = sch ^ (row & 7);
      GLOAD16(Bk + (long)row * ldB + sc * 8, &lds[buf][1][(r * 32 + wave * 8) * BK]);
    }
  };

  stage(0, 0);
  stage(1, 1);
  asm volatile("s_waitcnt vmcnt(8)" ::: "memory");
  __builtin_amdgcn_sched_barrier(0);
  __builtin_amdgcn_s_barrier();

  int cur = 0;
  for (int kt = 0; kt < nk; kt++) {
    const short* La = lds[cur][0];
    const short* Lb = lds[cur][1];
    bf16x8 av[2][4], bv[2][4];
#pragma unroll
    for (int s = 0; s < 2; s++) {
#pragma unroll
      for (int i = 0; i < 4; i++) {
        av[s][i] = *reinterpret_cast<const bf16x8*>(La + aOff[i][s]);
        bv[s][i] = *reinterpret_cast<const bf16x8*>(Lb + bOff[i][s]);
      }
    }
    asm volatile("s_waitcnt lgkmcnt(0)" ::: "memory");
    __builtin_amdgcn_sched_barrier(0);
    __builtin_amdgcn_s_barrier();
    __builtin_amdgcn_sched_barrier(0);

    if (kt + 2 < nk) {
      stage(cur, kt + 2);
      asm volatile("s_waitcnt vmcnt(8)" ::: "memory");
    } else if (kt + 1 < nk) {
      asm volatile("s_waitcnt vmcnt(0)" ::: "memory");
    }
    if (kt + 1 < nk) {
      __builtin_amdgcn_s_barrier();
      __builtin_amdgcn_sched_barrier(0);
    }

    __builtin_amdgcn_s_setprio(1);
#pragma unroll
    for (int s = 0; s < 2; s++)
#pragma unroll
      for (int i = 0; i < 4; i++)
#pragma unroll
        for (int j = 0; j < 4; j++)
          acc[i][j] = __builtin_amdgcn_mfma_f32_16x16x32_bf16(av[s][i], bv[s][j], acc[i][j], 0, 0, 0);
    __builtin_amdgcn_s_setprio(0);
    __builtin_amdgcn_sched_barrier(0);
    cur ^= 1;
  }

  const int rb4 = (lane >> 4) * 4;
  const int cl = lane & 15;
#pragma unroll
  for (int i = 0; i < 4; i++) {
#pragma unroll
    for (int j = 0; j < 4; j++) {
      const int gm = m0 + wr * 64 + i * 16 + rb4;
      const int gn = n0 + wc * 64 + j * 16 + cl;
      if (EPI == 0) {
        unsigned short* C = (unsigned short*)Cv + (long)bz * cBat;
#pragma unroll
        for (int r = 0; r < 4; r++)
          C[(long)(gm + r) * ldC + gn] = f2bf(acc[i][j][r] * scale);
      } else {
        float* C = (float*)Cv + (long)bz * cBat;
        const float bb = bias[gn];
#pragma unroll
        for (int r = 0; r < 4; r++)
          C[(long)(gm + r) * ldC + gn] = acc[i][j][r] + bb;
      }
    }
  }
}

// ---------------------------------------------------------------------------
// fused_prep: blocks [0,64) = Wvo GEMM (Wvo = Wo*Wv via A=Wob, B=Wvt, 128^2
// dbuf counted-vmcnt, bf16 out -> Wqkv rows [2048,3072));
// blocks [64,4160) = cast x -> Xbf. Inputs Wob/Wvt come from cast_w (prior
// dispatch), so no intra-dispatch dependency.
// ---------------------------------------------------------------------------
__global__ __launch_bounds__(256, 2)
void fused_prep(const float* __restrict__ x, unsigned short* __restrict__ xb,
                const unsigned short* __restrict__ Wob, const unsigned short* __restrict__ Wvt,
                unsigned short* __restrict__ WvoOut)
{
  __shared__ short lds[2][2][BM * BK];

  if (blockIdx.x >= 64) {
    const int blk = blockIdx.x - 64;
    const int i = (blk * 256 + (int)threadIdx.x) * 8;
    float4 a = *reinterpret_cast<const float4*>(x + i);
    float4 b = *reinterpret_cast<const float4*>(x + i + 4);
    union { unsigned short us[8]; uint4 u4; } pk;
    pk.us[0] = f2bf(a.x); pk.us[1] = f2bf(a.y); pk.us[2] = f2bf(a.z); pk.us[3] = f2bf(a.w);
    pk.us[4] = f2bf(b.x); pk.us[5] = f2bf(b.y); pk.us[6] = f2bf(b.z); pk.us[7] = f2bf(b.w);
    *reinterpret_cast<uint4*>(xb + i) = pk.u4;
    return;
  }

  // ---- Wvo GEMM: C[d][m] = sum_a Wo[d][a]*Wv[a][m]; M=N=K=1024
  const int by = blockIdx.x >> 3, bx = blockIdx.x & 7;
  const int m0 = by * BM, n0 = bx * BN;
  const unsigned short* Ab = Wob + (long)m0 * 1024;
  const unsigned short* Bb = Wvt + (long)n0 * 1024;

  const int tid = threadIdx.x;
  const int lane = tid & 63;
  const int wave = tid >> 6;
  const int wr = wave >> 1, wc = wave & 1;
  const int nk = 16;
  const int srow = tid >> 3;
  const int sch = tid & 7;

  const f32x4 fzero = {0.f, 0.f, 0.f, 0.f};
  f32x4 acc[4][4];
#pragma unroll
  for (int i = 0; i < 4; i++)
#pragma unroll
    for (int j = 0; j < 4; j++) acc[i][j] = fzero;

  int aOff[4][2], bOff[4][2];
#pragma unroll
  for (int i = 0; i < 4; i++) {
#pragma unroll
    for (int s = 0; s < 2; s++) {
      int ra = wr * 64 + i * 16 + (lane & 15);
      aOff[i][s] = ra * BK + (((s * 4 + (lane >> 4)) ^ (ra & 7)) * 8);
      int rb = wc * 64 + i * 16 + (lane & 15);
      bOff[i][s] = rb * BK + (((s * 4 + (lane >> 4)) ^ (rb & 7)) * 8);
    }
  }

  auto stage = [&](int buf, int kt) {
    const unsigned short* Ak = Ab + kt * BK;
    const unsigned short* Bk = Bb + kt * BK;
#pragma unroll
    for (int r = 0; r < 4; r++) {
      int row = r * 32 + srow;
      int sc = sch ^ (row & 7);
      GLOAD16(Ak + (long)row * 1024 + sc * 8, &lds[buf][0][(r * 32 + wave * 8) * BK]);
    }
#pragma unroll
    for (int r = 0; r < 4; r++) {
      int row = r * 32 + srow;
      int sc = sch ^ (row & 7);
      GLOAD16(Bk + (long)row * 1024 + sc * 8, &lds[buf][1][(r * 32 + wave * 8) * BK]);
    }
  };

  stage(0, 0);
  stage(1, 1);
  asm volatile("s_waitcnt vmcnt(8)" ::: "memory");
  __builtin_amdgcn_sched_barrier(0);
  __builtin_amdgcn_s_barrier();

  int cur = 0;
  for (int kt = 0; kt < nk; kt++) {
    const short* La = lds[cur][0];
    const short* Lb = lds[cur][1];
    bf16x8 av[2][4], bv[2][4];
#pragma unroll
    for (int s = 0; s < 2; s++) {
#pragma unroll
      for (int i = 0; i < 4; i++) {
        av[s][i] = *reinterpret_cast<const bf16x8*>(La + aOff[i][s]);
        bv[s][i] = *reinterpret_cast<const bf16x8*>(Lb + bOff[i][s]);
      }
    }
    asm volatile("s_waitcnt lgkmcnt(0)" ::: "memory");
    __builtin_amdgcn_sched_barrier(0);
    __builtin_amdgcn_s_barrier();
    __builtin_amdgcn_sched_barrier(0);

    if (kt + 2 < nk) {
      stage(cur, kt + 2);
      asm volatile("s_waitcnt vmcnt(8)" ::: "memory");
    } else if (kt + 1 < nk) {
      asm volatile("s_waitcnt vmcnt(0)" ::: "memory");
    }
    if (kt + 1 < nk) {
      __builtin_amdgcn_s_barrier();
      __builtin_amdgcn_sched_barrier(0);
    }

    __builtin_amdgcn_s_setprio(1);
#pragma unroll
    for (int s = 0; s < 2; s++)
#pragma unroll
      for (int i = 0; i < 4; i++)
#pragma unroll
        for (int j = 0; j < 4; j++)
          acc[i][j] = __builtin_amdgcn_mfma_f32_16x16x32_bf16(av[s][i], bv[s][j], acc[i][j], 0, 0, 0);
    __builtin_amdgcn_s_setprio(0);
    __builtin_amdgcn_sched_barrier(0);
    cur ^= 1;
  }

  const int rb4 = (lane >> 4) * 4;
  const int cl = lane & 15;
#pragma unroll
  for (int i = 0; i < 4; i++) {
#pragma unroll
    for (int j = 0; j < 4; j++) {
      const int gm = m0 + wr * 64 + i * 16 + rb4;
      const int gn = n0 + wc * 64 + j * 16 + cl;
#pragma unroll
      for (int r = 0; r < 4; r++)
        WvoOut[(long)(gm + r) * 1024 + gn] = f2bf(acc[i][j][r]);
    }
  }
}

// cast_w: blocks [0,512) Wq -> Wqkv[0:1024); [512,1024) Wk -> Wqkv[1024:2048);
// [1024,1536) Wo -> Wob; [1536,1792) transpose-cast Wv -> Wvt[m][a]=Wv[a][m].
__global__ __launch_bounds__(256)
void cast_w(const float* __restrict__ Wq, const float* __restrict__ Wk,
            const float* __restrict__ Wv, const float* __restrict__ Wo,
            unsigned short* __restrict__ Wqkv, unsigned short* __restrict__ Wob,
            unsigned short* __restrict__ Wvt)
{
  const int blk = blockIdx.x;
  const int tid = threadIdx.x;
  if (blk < 1536) {
    const int w = blk >> 9;                    // 0,1,2
    const int off = blk & 511;
    const float* src = (w == 0) ? Wq : (w == 1) ? Wk : Wo;
    unsigned short* dst = (w < 2) ? (Wqkv + (long)w * 1024 * 1024) : Wob;
    const int i = (off * 256 + tid) * 8;
    float4 a = *reinterpret_cast<const float4*>(src + i);
    float4 b = *reinterpret_cast<const float4*>(src + i + 4);
    union { unsigned short us[8]; uint4 u4; } pk;
    pk.us[0] = f2bf(a.x); pk.us[1] = f2bf(a.y); pk.us[2] = f2bf(a.z); pk.us[3] = f2bf(a.w);
    pk.us[4] = f2bf(b.x); pk.us[5] = f2bf(b.y); pk.us[6] = f2bf(b.z); pk.us[7] = f2bf(b.w);
    *reinterpret_cast<uint4*>(dst + i) = pk.u4;
    return;
  }
  // transpose-cast: tile (ta, tm) of 64x64; Wvt[m][a] = Wv[a][m]
  __shared__ float t[64][65];
  const int tile = blk - 1536;                 // 0..255
  const int a0 = (tile >> 4) * 64;
  const int m0 = (tile & 15) * 64;
#pragma unroll
  for (int i = 0; i < 4; i++) {
    const int row = (tid >> 4) + i * 16;       // a-offset 0..63
    const int col4 = tid & 15;                 // m-offset/4
    float4 f4 = *reinterpret_cast<const float4*>(Wv + (long)(a0 + row) * 1024 + m0 + col4 * 4);
    t[row][col4 * 4 + 0] = f4.x;
    t[row][col4 * 4 + 1] = f4.y;
    t[row][col4 * 4 + 2] = f4.z;
    t[row][col4 * 4 + 3] = f4.w;
  }
  __syncthreads();
#pragma unroll
  for (int j = 0; j < 2; j++) {
    const int mm = (tid >> 3) + j * 32;        // m-offset 0..63
    const int aa0 = (tid & 7) * 8;             // a-offset chunk
    union { unsigned short us[8]; uint4 u4; } pk;
#pragma unroll
    for (int u = 0; u < 8; u++) pk.us[u] = f2bf(t[aa0 + u][mm]);
    *reinterpret_cast<uint4*>(Wvt + (long)(m0 + mm) * 1024 + a0 + aa0) = pk.u4;
  }
}

// one WAVE per (q row); 4 rows per block; shfl-only reduction (no __syncthreads).
__global__ __launch_bounds__(256)
void softmax_rows(const unsigned short* __restrict__ Sb, const float* __restrict__ maskv,
                  unsigned short* __restrict__ P, int Sdim)
{
  const int wv = threadIdx.x >> 6;
  const int lane = threadIdx.x & 63;
  const int q = blockIdx.x * 4 + wv;
  const int b = blockIdx.y;
  const int kmax = (q & ~127) + 128;
  const unsigned short* row = Sb + ((long)b * Sdim + q) * Sdim;
  unsigned short* prow = P + ((long)b * Sdim + q) * Sdim;
  const float* mrow = maskv + (long)b * Sdim;
  const float mq = mrow[q];

  float v[4][8];
  float mx = -INFINITY;
#pragma unroll
  for (int c = 0; c < 4; c++) {
    const int k0 = c * 512 + lane * 8;
    if (c * 512 < kmax) {
      uint4 raw = *reinterpret_cast<const uint4*>(row + k0);
      const unsigned short* us = reinterpret_cast<const unsigned short*>(&raw);
      float4 ma = *reinterpret_cast<const float4*>(mrow + k0);
      float4 mb = *reinterpret_cast<const float4*>(mrow + k0 + 4);
      float mv[8] = {ma.x, ma.y, ma.z, ma.w, mb.x, mb.y, mb.z, mb.w};
#pragma unroll
      for (int u = 0; u < 8; u++) {
        const int k = k0 + u;
        const bool ok = (k <= q) && (mq * mv[u] == 1.0f);   // square_mask == 1 semantics
        v[c][u] = ok ? bf2f(us[u]) : -INFINITY;
        mx = fmaxf(mx, v[c][u]);
      }
    } else {
#pragma unroll
      for (int u = 0; u < 8; u++) v[c][u] = -INFINITY;
    }
  }
#pragma unroll
  for (int o = 32; o; o >>= 1) mx = fmaxf(mx, __shfl_xor(mx, o));

  float sm = 0.f;
#pragma unroll
  for (int c = 0; c < 4; c++)
#pragma unroll
    for (int u = 0; u < 8; u++) {
      v[c][u] = (v[c][u] > -INFINITY) ? __expf(v[c][u] - mx) : 0.f;
      sm += v[c][u];
    }
#pragma unroll
  for (int o = 32; o; o >>= 1) sm += __shfl_xor(sm, o);
  const float inv = 1.0f / sm;

#pragma unroll
  for (int c = 0; c < 4; c++) {
    if (c * 512 < kmax) {
      union { unsigned short us[8]; uint4 u4; } pk;
#pragma unroll
      for (int u = 0; u < 8; u++) pk.us[u] = f2bf(v[c][u] * inv);
      *reinterpret_cast<uint4*>(prow + c * 512 + lane * 8) = pk.u4;
    }
  }
}

extern "C" void kernel_launch(void* const* d_in, const int* in_sizes, int n_in,
                              void* d_out, int out_size, void* d_ws, size_t ws_size,
                              hipStream_t stream)
{
  const int B = 4, S = 2048, D = 1024;
  const float* x  = (const float*)d_in[0];
  const float* mk = (const float*)d_in[1];
  const float* Wq = (const float*)d_in[2];
  const float* Wk = (const float*)d_in[3];
  const float* Wv = (const float*)d_in[4];
  const float* Wo = (const float*)d_in[5];
  const float* bo = (const float*)d_in[6];
  float* out = (float*)d_out;

  char* ws = (char*)d_ws;
  const long MB = 1024L * 1024L;
  unsigned short* Xbf  = (unsigned short*)(ws + 0);        // 16MB; dead after QKV
  unsigned short* Qb   = (unsigned short*)(ws + 16 * MB);  // 16MB [8192][1024]; -> P
  unsigned short* Kb   = (unsigned short*)(ws + 32 * MB);  // 16MB [8192][1024]; -> P
  unsigned short* VWt  = (unsigned short*)(ws + 48 * MB);  // 16MB VW^T per batch [D][S]
  unsigned short* Wqkv = (unsigned short*)(ws + 64 * MB);  // 6MB [3072][1024] Wq|Wk|Wvo
  unsigned short* Wob  = (unsigned short*)(ws + 70 * MB);  // 2MB
  unsigned short* Sbuf = (unsigned short*)(ws + 72 * MB);  // 32MB bf16 logits
  unsigned short* Wvt  = Sbuf;                             // 2MB overlay; dead before S writes
  unsigned short* P    = Qb;                               // 32MB over dead Q+K

  if (ws_size < (size_t)(104 * MB)) {
    fprintf(stderr, "kernel_launch: ws too small (%zu bytes, need 104MB)\n", ws_size);
    return;
  }

  // 1) weight casts + Wv transpose-cast
  cast_w<<<dim3(1792), dim3(256), 0, stream>>>(Wq, Wk, Wv, Wo, Wqkv, Wob, Wvt);
  // 2) fused: Wvo = Wo*Wv (64 GEMM blocks) || cast x (4096 blocks)
  fused_prep<<<dim3(4160), dim3(256), 0, stream>>>(x, Xbf, Wob, Wvt, Wqkv + 2048L * 1024);

  const dim3 blk(256);
  // 3) fused QKV: M=8192, N=3072, K=1024 -> Qb, Kb, VWt (V-cols now compute X*Wvo^T)
  dim3 gQKV(3072 / BN, 8192 / BM, 1);
  gemm_sb<4><<<gQKV, blk, 0, stream>>>(Xbf, Wqkv, Qb, Kb, VWt,
                                       1024, 1024, 1024, 0,
                                       0, 0, 0, 0, 1.0f);
  // 4) S = Q K^T / 32 (bf16 out), causal tile-skip, per batch
  dim3 gS(2048 / BN, 2048 / BM, 4);
  gemm_sb<0><<<gS, blk, 0, stream>>>(Qb, Kb, Sbuf, nullptr, nullptr,
                                     1024, 1024, 1024, 2048,
                                     (long)S * 1024, (long)S * 1024, (long)S * S,
                                     1, 0.03125f);
  // 5) softmax -> P bf16
  softmax_rows<<<dim3(512, 4), blk, 0, stream>>>(Sbuf, mk, P, 2048);
  // 6) out = P * VWt^T + bo (fp32, direct) — F GEMM eliminated by Wvo fold
  dim3 gO(1024 / BN, 2048 / BM, 4);
  gemm_db<2><<<gO, blk, 0, stream>>>(P, VWt, out, bo,
                                     2048, 2048, 2048, 1024,
                                     (long)S * S, (long)D * S, (long)S * D,
                                     1, 1.0f, 1);
}

// Round 9
// 163.443 us; speedup vs baseline: 1.3148x; 1.0269x over previous
//
#include <hip/hip_runtime.h>
#include <hip/hip_bf16.h>
#include <cstdio>

typedef __bf16 bf16x8 __attribute__((ext_vector_type(8)));
typedef float f32x4 __attribute__((ext_vector_type(4)));

#define BM 128
#define BN 128
#define BK 64

__device__ __forceinline__ unsigned short f2bf(float f) {
  union { float f; unsigned u; } v; v.f = f;
  unsigned u = v.u;
  return (unsigned short)((u + 0x7FFFu + ((u >> 16) & 1u)) >> 16);
}

__device__ __forceinline__ float bf2f(unsigned short s) {
  union { unsigned u; float f; } v; v.u = ((unsigned)s) << 16;
  return v.f;
}

#define GLOAD16(gsrc, ldst) \
  __builtin_amdgcn_global_load_lds((const __attribute__((address_space(1))) void*)(gsrc), \
                                   (__attribute__((address_space(3))) void*)(ldst), 16, 0, 0)

// ---------------------------------------------------------------------------
// Shared single-buffered K-loop body (m97-style, verified): ld == 1024 for all
// operands in dispA/dispB; nk = 16. Declared as a macro over (Ab, Bb, lds,
// acc, aOff, bOff, srow, sch, wave) to keep the instruction stream identical.
// ---------------------------------------------------------------------------
#define SB_KLOOP(Ab, Bb)                                                        \
  for (int kt = 0; kt < 16; kt++) {                                             \
    const unsigned short* Ak = (Ab) + kt * BK;                                  \
    const unsigned short* Bk = (Bb) + kt * BK;                                  \
    _Pragma("unroll")                                                           \
    for (int r = 0; r < 4; r++) {                                               \
      int row = r * 32 + srow;                                                  \
      int sc = sch ^ (row & 7);                                                 \
      GLOAD16(Ak + (long)row * 1024 + sc * 8, &lds[0][(r * 32 + wave * 8) * BK]);\
    }                                                                           \
    _Pragma("unroll")                                                           \
    for (int r = 0; r < 4; r++) {                                               \
      int row = r * 32 + srow;                                                  \
      int sc = sch ^ (row & 7);                                                 \
      GLOAD16(Bk + (long)row * 1024 + sc * 8, &lds[1][(r * 32 + wave * 8) * BK]);\
    }                                                                           \
    __syncthreads();                                                            \
    _Pragma("unroll")                                                           \
    for (int s = 0; s < 2; s++) {                                               \
      bf16x8 av[4], bv[4];                                                      \
      _Pragma("unroll")                                                         \
      for (int i = 0; i < 4; i++) av[i] = *reinterpret_cast<const bf16x8*>(lds[0] + aOff[i][s]); \
      _Pragma("unroll")                                                         \
      for (int j = 0; j < 4; j++) bv[j] = *reinterpret_cast<const bf16x8*>(lds[1] + bOff[j][s]); \
      _Pragma("unroll")                                                         \
      for (int i = 0; i < 4; i++)                                               \
        _Pragma("unroll")                                                       \
        for (int j = 0; j < 4; j++)                                             \
          acc[i][j] = __builtin_amdgcn_mfma_f32_16x16x32_bf16(av[i], bv[j], acc[i][j], 0, 0, 0); \
    }                                                                           \
    __syncthreads();                                                            \
  }

#define SB_PREAMBLE                                                             \
  const int tid = threadIdx.x;                                                  \
  const int lane = tid & 63;                                                    \
  const int wave = tid >> 6;                                                    \
  const int wr = wave >> 1, wc = wave & 1;                                      \
  const int srow = tid >> 3;                                                    \
  const int sch = tid & 7;                                                      \
  const f32x4 fzero = {0.f, 0.f, 0.f, 0.f};                                     \
  f32x4 acc[4][4];                                                              \
  _Pragma("unroll")                                                             \
  for (int i = 0; i < 4; i++)                                                   \
    _Pragma("unroll")                                                           \
    for (int j = 0; j < 4; j++) acc[i][j] = fzero;                              \
  int aOff[4][2], bOff[4][2];                                                   \
  _Pragma("unroll")                                                             \
  for (int i = 0; i < 4; i++) {                                                 \
    _Pragma("unroll")                                                           \
    for (int s = 0; s < 2; s++) {                                               \
      int ra = wr * 64 + i * 16 + (lane & 15);                                  \
      aOff[i][s] = ra * BK + (((s * 4 + (lane >> 4)) ^ (ra & 7)) * 8);          \
      int rb = wc * 64 + i * 16 + (lane & 15);                                  \
      bOff[i][s] = rb * BK + (((s * 4 + (lane >> 4)) ^ (rb & 7)) * 8);          \
    }                                                                           \
  }

// ---------------------------------------------------------------------------
// dispA: blocks [0,1024) = QK projection GEMM (M=8192, N=2048, K=1024);
//        blocks [1024,1088) = Wvo = Wo*Wv GEMM (M=N=K=1024).
// Both depend only on cast_all2; Wvo hides under QK.
// ---------------------------------------------------------------------------
__global__ __launch_bounds__(256, 3)
void dispA(const unsigned short* __restrict__ Xbf, const unsigned short* __restrict__ Wqk,
           const unsigned short* __restrict__ Wob, const unsigned short* __restrict__ Wvt,
           unsigned short* __restrict__ Qb, unsigned short* __restrict__ Kb,
           unsigned short* __restrict__ Wvo)
{
  __shared__ short lds[2][BM * BK];
  const int flat = blockIdx.x;
  const bool isQK = flat < 1024;
  int m0, n0;
  const unsigned short *Ab, *Bb;
  if (isQK) {
    const int swz = (flat & 7) * 128 + (flat >> 3);   // m204, nwg=1024 (r=0)
    const int bx = swz & 15, by = swz >> 4;           // gx=16
    m0 = by * BM; n0 = bx * BN;
    Ab = Xbf + (long)m0 * 1024;
    Bb = Wqk + (long)n0 * 1024;
  } else {
    const int t = flat - 1024;                        // 0..63, 8x8 grid
    m0 = (t >> 3) * BM; n0 = (t & 7) * BN;
    Ab = Wob + (long)m0 * 1024;
    Bb = Wvt + (long)n0 * 1024;
  }

  SB_PREAMBLE
  SB_KLOOP(Ab, Bb)

  const int rb4 = (lane >> 4) * 4;
  const int cl = lane & 15;
#pragma unroll
  for (int i = 0; i < 4; i++) {
#pragma unroll
    for (int j = 0; j < 4; j++) {
      const int gm = m0 + wr * 64 + i * 16 + rb4;
      const int gn = n0 + wc * 64 + j * 16 + cl;
      if (isQK) {
        if (gn < 1024) {
#pragma unroll
          for (int r = 0; r < 4; r++)
            Qb[(long)(gm + r) * 1024 + gn] = f2bf(acc[i][j][r]);
        } else {
#pragma unroll
          for (int r = 0; r < 4; r++)
            Kb[(long)(gm + r) * 1024 + (gn - 1024)] = f2bf(acc[i][j][r]);
        }
      } else {
#pragma unroll
        for (int r = 0; r < 4; r++)
          Wvo[(long)(gm + r) * 1024 + gn] = f2bf(acc[i][j][r]);
      }
    }
  }
}

// ---------------------------------------------------------------------------
// dispB: blocks [0,512) = VW GEMM (VW = X*Wvo^T, transposed store -> VWt);
//        blocks [512,1056) = S GEMM packed lower-triangular (136 tiles x 4 batches).
// Both depend only on dispA (+casts).
// ---------------------------------------------------------------------------
__global__ __launch_bounds__(256, 3)
void dispB(const unsigned short* __restrict__ Xbf, const unsigned short* __restrict__ Wvo,
           const unsigned short* __restrict__ Qb, const unsigned short* __restrict__ Kb,
           unsigned short* __restrict__ VWt, unsigned short* __restrict__ Sb)
{
  __shared__ short lds[2][BM * BK];
  const int flat = blockIdx.x;
  const bool isVW = flat < 512;
  int m0, n0, bz = 0;
  const unsigned short *Ab, *Bb;
  if (isVW) {
    const int swz = (flat & 7) * 64 + (flat >> 3);    // m204, nwg=512 (r=0)
    const int bx = swz & 7, by = swz >> 3;            // gx=8
    m0 = by * BM; n0 = bx * BN;
    Ab = Xbf + (long)m0 * 1024;
    Bb = Wvo + (long)n0 * 1024;
  } else {
    const int t = flat - 512;                         // 0..543
    bz = t / 136;
    const int tt = t - bz * 136;
    const int swz = (tt & 7) * 17 + (tt >> 3);        // m204, nwg=136 (17x8, r=0)
    int i = (int)((sqrtf(8.f * (float)swz + 1.f) - 1.f) * 0.5f);
    while ((i + 1) * (i + 2) / 2 <= swz) ++i;         // guard fp rounding
    while (i * (i + 1) / 2 > swz) --i;
    const int j = swz - i * (i + 1) / 2;
    m0 = i * BM; n0 = j * BN;
    Ab = Qb + ((long)bz * 2048 + m0) * 1024;
    Bb = Kb + ((long)bz * 2048 + n0) * 1024;
  }

  SB_PREAMBLE
  SB_KLOOP(Ab, Bb)

  const int rb4 = (lane >> 4) * 4;
  const int cl = lane & 15;
#pragma unroll
  for (int i = 0; i < 4; i++) {
#pragma unroll
    for (int j = 0; j < 4; j++) {
      const int gm = m0 + wr * 64 + i * 16 + rb4;
      const int gn = n0 + wc * 64 + j * 16 + cl;
      if (isVW) {
        // transposed store: VWt[b][d=gn][s], b = gm>>11, s = gm&2047
        const int b = gm >> 11;
        const int sIdx = gm & 2047;
        unsigned short* C = VWt + (long)b * (2048L * 1024) + (long)gn * 2048 + sIdx;
        ushort4 pk;
        pk.x = f2bf(acc[i][j][0]);
        pk.y = f2bf(acc[i][j][1]);
        pk.z = f2bf(acc[i][j][2]);
        pk.w = f2bf(acc[i][j][3]);
        *reinterpret_cast<ushort4*>(C) = pk;
      } else {
        unsigned short* C = Sb + (long)bz * (2048L * 2048);
#pragma unroll
        for (int r = 0; r < 4; r++)
          C[(long)(gm + r) * 2048 + gn] = f2bf(acc[i][j][r] * 0.03125f);
      }
    }
  }
}

// ---------------------------------------------------------------------------
// Double-buffered counted-vmcnt 128x128 GEMM-BT (R3-verified): PV -> out fp32+bias.
// ---------------------------------------------------------------------------
__global__ __launch_bounds__(256, 2)
void gemm_pv(const unsigned short* __restrict__ A, const unsigned short* __restrict__ B,
             float* __restrict__ Cv, const float* __restrict__ bias,
             int K, int ldA, int ldB, int ldC,
             long aBat, long bBat, long cBat)
{
  const int gx = gridDim.x;
  const int nwg = gx * gridDim.y;
  const int flat = blockIdx.y * gx + blockIdx.x;
  const int qch = nwg >> 3, rch = nwg & 7;
  const int xcd = flat & 7, idx = flat >> 3;
  const int swz = (xcd < rch ? xcd * (qch + 1) : rch * (qch + 1) + (xcd - rch) * qch) + idx;
  const int bx = swz % gx;
  int by = swz / gx;
  by = gridDim.y - 1 - by;                   // revM: heavy tiles first

  const int m0 = by * BM;
  const int n0 = bx * BN;
  const int bz = blockIdx.z;

  const unsigned short* Ab = A + (long)bz * aBat + (long)m0 * ldA;
  const unsigned short* Bb = B + (long)bz * bBat + (long)n0 * ldB;

  __shared__ short lds[2][2][BM * BK];

  const int tid = threadIdx.x;
  const int lane = tid & 63;
  const int wave = tid >> 6;
  const int wr = wave >> 1, wc = wave & 1;

  const int Keff = min(K, m0 + BM);          // causal K-limit
  const int nk = Keff / BK;

  const int srow = tid >> 3;
  const int sch = tid & 7;

  const f32x4 fzero = {0.f, 0.f, 0.f, 0.f};
  f32x4 acc[4][4];
#pragma unroll
  for (int i = 0; i < 4; i++)
#pragma unroll
    for (int j = 0; j < 4; j++) acc[i][j] = fzero;

  int aOff[4][2], bOff[4][2];
#pragma unroll
  for (int i = 0; i < 4; i++) {
#pragma unroll
    for (int s = 0; s < 2; s++) {
      int ra = wr * 64 + i * 16 + (lane & 15);
      aOff[i][s] = ra * BK + (((s * 4 + (lane >> 4)) ^ (ra & 7)) * 8);
      int rb = wc * 64 + i * 16 + (lane & 15);
      bOff[i][s] = rb * BK + (((s * 4 + (lane >> 4)) ^ (rb & 7)) * 8);
    }
  }

  auto stage = [&](int buf, int kt) {
    const unsigned short* Ak = Ab + kt * BK;
    const unsigned short* Bk = Bb + kt * BK;
#pragma unroll
    for (int r = 0; r < 4; r++) {
      int row = r * 32 + srow;
      int sc = sch ^ (row & 7);
      GLOAD16(Ak + (long)row * ldA + sc * 8, &lds[buf][0][(r * 32 + wave * 8) * BK]);
    }
#pragma unroll
    for (int r = 0; r < 4; r++) {
      int row = r * 32 + srow;
      int sc = sch ^ (row & 7);
      GLOAD16(Bk + (long)row * ldB + sc * 8, &lds[buf][1][(r * 32 + wave * 8) * BK]);
    }
  };

  stage(0, 0);
  stage(1, 1);
  asm volatile("s_waitcnt vmcnt(8)" ::: "memory");
  __builtin_amdgcn_sched_barrier(0);
  __builtin_amdgcn_s_barrier();

  int cur = 0;
  for (int kt = 0; kt < nk; kt++) {
    const short* La = lds[cur][0];
    const short* Lb = lds[cur][1];
    bf16x8 av[2][4], bv[2][4];
#pragma unroll
    for (int s = 0; s < 2; s++) {
#pragma unroll
      for (int i = 0; i < 4; i++) {
        av[s][i] = *reinterpret_cast<const bf16x8*>(La + aOff[i][s]);
        bv[s][i] = *reinterpret_cast<const bf16x8*>(Lb + bOff[i][s]);
      }
    }
    asm volatile("s_waitcnt lgkmcnt(0)" ::: "memory");
    __builtin_amdgcn_sched_barrier(0);
    __builtin_amdgcn_s_barrier();
    __builtin_amdgcn_sched_barrier(0);

    if (kt + 2 < nk) {
      stage(cur, kt + 2);
      asm volatile("s_waitcnt vmcnt(8)" ::: "memory");
    } else if (kt + 1 < nk) {
      asm volatile("s_waitcnt vmcnt(0)" ::: "memory");
    }
    if (kt + 1 < nk) {
      __builtin_amdgcn_s_barrier();
      __builtin_amdgcn_sched_barrier(0);
    }

    __builtin_amdgcn_s_setprio(1);
#pragma unroll
    for (int s = 0; s < 2; s++)
#pragma unroll
      for (int i = 0; i < 4; i++)
#pragma unroll
        for (int j = 0; j < 4; j++)
          acc[i][j] = __builtin_amdgcn_mfma_f32_16x16x32_bf16(av[s][i], bv[s][j], acc[i][j], 0, 0, 0);
    __builtin_amdgcn_s_setprio(0);
    __builtin_amdgcn_sched_barrier(0);
    cur ^= 1;
  }

  const int rb4 = (lane >> 4) * 4;
  const int cl = lane & 15;
#pragma unroll
  for (int i = 0; i < 4; i++) {
#pragma unroll
    for (int j = 0; j < 4; j++) {
      const int gm = m0 + wr * 64 + i * 16 + rb4;
      const int gn = n0 + wc * 64 + j * 16 + cl;
      float* C = Cv + (long)bz * cBat;
      const float bb = bias[gn];
#pragma unroll
      for (int r = 0; r < 4; r++)
        C[(long)(gm + r) * ldC + gn] = acc[i][j][r] + bb;
    }
  }
}

// one WAVE per (q row); 4 rows per block; shfl-only reduction.
__global__ __launch_bounds__(256)
void softmax_rows(const unsigned short* __restrict__ Sb, const float* __restrict__ maskv,
                  unsigned short* __restrict__ P, int Sdim)
{
  const int wv = threadIdx.x >> 6;
  const int lane = threadIdx.x & 63;
  const int q = blockIdx.x * 4 + wv;
  const int b = blockIdx.y;
  const int kmax = (q & ~127) + 128;
  const unsigned short* row = Sb + ((long)b * Sdim + q) * Sdim;
  unsigned short* prow = P + ((long)b * Sdim + q) * Sdim;
  const float* mrow = maskv + (long)b * Sdim;
  const float mq = mrow[q];

  float v[4][8];
  float mx = -INFINITY;
#pragma unroll
  for (int c = 0; c < 4; c++) {
    const int k0 = c * 512 + lane * 8;
    if (c * 512 < kmax) {
      uint4 raw = *reinterpret_cast<const uint4*>(row + k0);
      const unsigned short* us = reinterpret_cast<const unsigned short*>(&raw);
      float4 ma = *reinterpret_cast<const float4*>(mrow + k0);
      float4 mb = *reinterpret_cast<const float4*>(mrow + k0 + 4);
      float mv[8] = {ma.x, ma.y, ma.z, ma.w, mb.x, mb.y, mb.z, mb.w};
#pragma unroll
      for (int u = 0; u < 8; u++) {
        const int k = k0 + u;
        const bool ok = (k <= q) && (mq * mv[u] == 1.0f);   // square_mask == 1 semantics
        v[c][u] = ok ? bf2f(us[u]) : -INFINITY;
        mx = fmaxf(mx, v[c][u]);
      }
    } else {
#pragma unroll
      for (int u = 0; u < 8; u++) v[c][u] = -INFINITY;
    }
  }
#pragma unroll
  for (int o = 32; o; o >>= 1) mx = fmaxf(mx, __shfl_xor(mx, o));

  float sm = 0.f;
#pragma unroll
  for (int c = 0; c < 4; c++)
#pragma unroll
    for (int u = 0; u < 8; u++) {
      v[c][u] = (v[c][u] > -INFINITY) ? __expf(v[c][u] - mx) : 0.f;
      sm += v[c][u];
    }
#pragma unroll
  for (int o = 32; o; o >>= 1) sm += __shfl_xor(sm, o);
  const float inv = 1.0f / sm;

#pragma unroll
  for (int c = 0; c < 4; c++) {
    if (c * 512 < kmax) {
      union { unsigned short us[8]; uint4 u4; } pk;
#pragma unroll
      for (int u = 0; u < 8; u++) pk.us[u] = f2bf(v[c][u] * inv);
      *reinterpret_cast<uint4*>(prow + c * 512 + lane * 8) = pk.u4;
    }
  }
}

// ---------------------------------------------------------------------------
// cast_all2 — ALL casts in one dispatch:
// [0,4096)      x -> Xbf
// [4096,4608)   Wq -> Wqk[0:1024)
// [4608,5120)   Wk -> Wqk[1024:2048)
// [5120,5632)   Wo -> Wob
// [5632,5888)   Wv transpose-cast -> Wvt[m][a] = Wv[a][m]
// ---------------------------------------------------------------------------
__global__ __launch_bounds__(256)
void cast_all2(const float* __restrict__ x, const float* __restrict__ Wq,
               const float* __restrict__ Wk, const float* __restrict__ Wv,
               const float* __restrict__ Wo,
               unsigned short* __restrict__ xb, unsigned short* __restrict__ Wqk,
               unsigned short* __restrict__ Wob, unsigned short* __restrict__ Wvt)
{
  __shared__ float t[64][65];
  const int blk = blockIdx.x;
  const int tid = threadIdx.x;
  if (blk < 5632) {
    const float* src;
    unsigned short* dst;
    int i;
    if (blk < 4096) {
      src = x; dst = xb; i = (blk * 256 + tid) * 8;
    } else {
      const int w = (blk - 4096) >> 9;          // 0,1,2
      const int off = (blk - 4096) & 511;
      src = (w == 0) ? Wq : (w == 1) ? Wk : Wo;
      dst = (w == 0) ? Wqk : (w == 1) ? (Wqk + 1024L * 1024) : Wob;
      i = (off * 256 + tid) * 8;
    }
    float4 a = *reinterpret_cast<const float4*>(src + i);
    float4 b = *reinterpret_cast<const float4*>(src + i + 4);
    union { unsigned short us[8]; uint4 u4; } pk;
    pk.us[0] = f2bf(a.x); pk.us[1] = f2bf(a.y); pk.us[2] = f2bf(a.z); pk.us[3] = f2bf(a.w);
    pk.us[4] = f2bf(b.x); pk.us[5] = f2bf(b.y); pk.us[6] = f2bf(b.z); pk.us[7] = f2bf(b.w);
    *reinterpret_cast<uint4*>(dst + i) = pk.u4;
    return;
  }
  // Wv transpose-cast: 64x64 tile per block
  const int tile = blk - 5632;                 // 0..255
  const int a0 = (tile >> 4) * 64;
  const int m0 = (tile & 15) * 64;
#pragma unroll
  for (int i = 0; i < 4; i++) {
    const int row = (tid >> 4) + i * 16;
    const int col4 = tid & 15;
    float4 f4 = *reinterpret_cast<const float4*>(Wv + (long)(a0 + row) * 1024 + m0 + col4 * 4);
    t[row][col4 * 4 + 0] = f4.x;
    t[row][col4 * 4 + 1] = f4.y;
    t[row][col4 * 4 + 2] = f4.z;
    t[row][col4 * 4 + 3] = f4.w;
  }
  __syncthreads();
#pragma unroll
  for (int j = 0; j < 2; j++) {
    const int mm = (tid >> 3) + j * 32;
    const int aa0 = (tid & 7) * 8;
    union { unsigned short us[8]; uint4 u4; } pk;
#pragma unroll
    for (int u = 0; u < 8; u++) pk.us[u] = f2bf(t[aa0 + u][mm]);
    *reinterpret_cast<uint4*>(Wvt + (long)(m0 + mm) * 1024 + a0 + aa0) = pk.u4;
  }
}

extern "C" void kernel_launch(void* const* d_in, const int* in_sizes, int n_in,
                              void* d_out, int out_size, void* d_ws, size_t ws_size,
                              hipStream_t stream)
{
  const int B = 4, S = 2048, D = 1024;
  const float* x  = (const float*)d_in[0];
  const float* mk = (const float*)d_in[1];
  const float* Wq = (const float*)d_in[2];
  const float* Wk = (const float*)d_in[3];
  const float* Wv = (const float*)d_in[4];
  const float* Wo = (const float*)d_in[5];
  const float* bo = (const float*)d_in[6];
  float* out = (float*)d_out;

  char* ws = (char*)d_ws;
  const long MB = 1024L * 1024L;
  unsigned short* Xbf  = (unsigned short*)(ws + 0);        // 16MB (live through dispB)
  unsigned short* Qb   = (unsigned short*)(ws + 16 * MB);  // 16MB [8192][1024]; -> P
  unsigned short* Kb   = (unsigned short*)(ws + 32 * MB);  // 16MB [8192][1024]; -> P
  unsigned short* VWt  = (unsigned short*)(ws + 48 * MB);  // 16MB VW^T per batch [D][S]
  unsigned short* Wqk  = (unsigned short*)(ws + 64 * MB);  // 4MB [2048][1024] Wq|Wk
  unsigned short* Wvo  = (unsigned short*)(ws + 68 * MB);  // 2MB [1024][1024]
  unsigned short* Wob  = (unsigned short*)(ws + 70 * MB);  // 2MB
  unsigned short* Sbuf = (unsigned short*)(ws + 72 * MB);  // 32MB bf16 logits
  unsigned short* Wvt  = Sbuf;                             // 2MB overlay (dead before S writes)
  unsigned short* P    = Qb;                               // 32MB over dead Q+K

  if (ws_size < (size_t)(104 * MB)) {
    fprintf(stderr, "kernel_launch: ws too small (%zu bytes, need 104MB)\n", ws_size);
    return;
  }

  // 1) all casts (x, Wq, Wk, Wo, Wv^T) in one dispatch
  cast_all2<<<dim3(5888), dim3(256), 0, stream>>>(x, Wq, Wk, Wv, Wo, Xbf, Wqk, Wob, Wvt);
  // 2) dispA: QK projection (1024 blocks) || Wvo = Wo*Wv (64 blocks)
  dispA<<<dim3(1088), dim3(256), 0, stream>>>(Xbf, Wqk, Wob, Wvt, Qb, Kb, Wvo);
  // 3) dispB: VW = X*Wvo^T transposed (512 blocks) || S = Q K^T/32 triangular (544 blocks)
  dispB<<<dim3(1056), dim3(256), 0, stream>>>(Xbf, Wvo, Qb, Kb, VWt, Sbuf);
  // 4) softmax -> P bf16
  softmax_rows<<<dim3(512, 4), dim3(256), 0, stream>>>(Sbuf, mk, P, 2048);
  // 5) out = P * VWt^T + bo (fp32 direct, causal K-limit, heavy tiles first)
  dim3 gO(1024 / BN, 2048 / BM, 4);
  gemm_pv<<<gO, dim3(256), 0, stream>>>(P, VWt, out, bo,
                                        2048, 2048, 2048, 1024,
                                        (long)S * S, (long)D * S, (long)S * D);
}

// Round 10
// 158.439 us; speedup vs baseline: 1.3563x; 1.0316x over previous
//
#include <hip/hip_runtime.h>
#include <hip/hip_bf16.h>
#include <cstdio>

typedef __bf16 bf16x8 __attribute__((ext_vector_type(8)));
typedef float f32x4 __attribute__((ext_vector_type(4)));

#define BM 128
#define BN 128
#define BK 64

__device__ __forceinline__ unsigned short f2bf(float f) {
  union { float f; unsigned u; } v; v.f = f;
  unsigned u = v.u;
  return (unsigned short)((u + 0x7FFFu + ((u >> 16) & 1u)) >> 16);
}

__device__ __forceinline__ float bf2f(unsigned short s) {
  union { unsigned u; float f; } v; v.u = ((unsigned)s) << 16;
  return v.f;
}

#define GLOAD16(gsrc, ldst) \
  __builtin_amdgcn_global_load_lds((const __attribute__((address_space(1))) void*)(gsrc), \
                                   (__attribute__((address_space(3))) void*)(ldst), 16, 0, 0)

// ---------------------------------------------------------------------------
// Shared single-buffered K-loop body (m97-style, verified): ld == 1024, nk=16.
// ---------------------------------------------------------------------------
#define SB_KLOOP(Ab, Bb)                                                        \
  for (int kt = 0; kt < 16; kt++) {                                             \
    const unsigned short* Ak = (Ab) + kt * BK;                                  \
    const unsigned short* Bk = (Bb) + kt * BK;                                  \
    _Pragma("unroll")                                                           \
    for (int r = 0; r < 4; r++) {                                               \
      int row = r * 32 + srow;                                                  \
      int sc = sch ^ (row & 7);                                                 \
      GLOAD16(Ak + (long)row * 1024 + sc * 8, &lds[0][(r * 32 + wave * 8) * BK]);\
    }                                                                           \
    _Pragma("unroll")                                                           \
    for (int r = 0; r < 4; r++) {                                               \
      int row = r * 32 + srow;                                                  \
      int sc = sch ^ (row & 7);                                                 \
      GLOAD16(Bk + (long)row * 1024 + sc * 8, &lds[1][(r * 32 + wave * 8) * BK]);\
    }                                                                           \
    __syncthreads();                                                            \
    _Pragma("unroll")                                                           \
    for (int s = 0; s < 2; s++) {                                               \
      bf16x8 av[4], bv[4];                                                      \
      _Pragma("unroll")                                                         \
      for (int i = 0; i < 4; i++) av[i] = *reinterpret_cast<const bf16x8*>(lds[0] + aOff[i][s]); \
      _Pragma("unroll")                                                         \
      for (int j = 0; j < 4; j++) bv[j] = *reinterpret_cast<const bf16x8*>(lds[1] + bOff[j][s]); \
      _Pragma("unroll")                                                         \
      for (int i = 0; i < 4; i++)                                               \
        _Pragma("unroll")                                                       \
        for (int j = 0; j < 4; j++)                                             \
          acc[i][j] = __builtin_amdgcn_mfma_f32_16x16x32_bf16(av[i], bv[j], acc[i][j], 0, 0, 0); \
    }                                                                           \
    __syncthreads();                                                            \
  }

#define SB_PREAMBLE                                                             \
  const int tid = threadIdx.x;                                                  \
  const int lane = tid & 63;                                                    \
  const int wave = tid >> 6;                                                    \
  const int wr = wave >> 1, wc = wave & 1;                                      \
  const int srow = tid >> 3;                                                    \
  const int sch = tid & 7;                                                      \
  const f32x4 fzero = {0.f, 0.f, 0.f, 0.f};                                     \
  f32x4 acc[4][4];                                                              \
  _Pragma("unroll")                                                             \
  for (int i = 0; i < 4; i++)                                                   \
    _Pragma("unroll")                                                           \
    for (int j = 0; j < 4; j++) acc[i][j] = fzero;                              \
  int aOff[4][2], bOff[4][2];                                                   \
  _Pragma("unroll")                                                             \
  for (int i = 0; i < 4; i++) {                                                 \
    _Pragma("unroll")                                                           \
    for (int s = 0; s < 2; s++) {                                               \
      int ra = wr * 64 + i * 16 + (lane & 15);                                  \
      aOff[i][s] = ra * BK + (((s * 4 + (lane >> 4)) ^ (ra & 7)) * 8);          \
      int rb = wc * 64 + i * 16 + (lane & 15);                                  \
      bOff[i][s] = rb * BK + (((s * 4 + (lane >> 4)) ^ (rb & 7)) * 8);          \
    }                                                                           \
  }

// ---------------------------------------------------------------------------
// dispA: blocks [0,1024) = QK projection GEMM; [1024,1088) = Wvo = Wo*Wv.
// 5 blocks/CU -> 1088 blocks fit in a single occupancy round.
// ---------------------------------------------------------------------------
__global__ __launch_bounds__(256, 5)
void dispA(const unsigned short* __restrict__ Xbf, const unsigned short* __restrict__ Wqk,
           const unsigned short* __restrict__ Wob, const unsigned short* __restrict__ Wvt,
           unsigned short* __restrict__ Qb, unsigned short* __restrict__ Kb,
           unsigned short* __restrict__ Wvo)
{
  __shared__ short lds[2][BM * BK];
  const int flat = blockIdx.x;
  const bool isQK = flat < 1024;
  int m0, n0;
  const unsigned short *Ab, *Bb;
  if (isQK) {
    const int swz = (flat & 7) * 128 + (flat >> 3);   // m204, nwg=1024 (r=0)
    const int bx = swz & 15, by = swz >> 4;           // gx=16
    m0 = by * BM; n0 = bx * BN;
    Ab = Xbf + (long)m0 * 1024;
    Bb = Wqk + (long)n0 * 1024;
  } else {
    const int t = flat - 1024;                        // 0..63, 8x8 grid
    m0 = (t >> 3) * BM; n0 = (t & 7) * BN;
    Ab = Wob + (long)m0 * 1024;
    Bb = Wvt + (long)n0 * 1024;
  }

  SB_PREAMBLE
  SB_KLOOP(Ab, Bb)

  const int rb4 = (lane >> 4) * 4;
  const int cl = lane & 15;
#pragma unroll
  for (int i = 0; i < 4; i++) {
#pragma unroll
    for (int j = 0; j < 4; j++) {
      const int gm = m0 + wr * 64 + i * 16 + rb4;
      const int gn = n0 + wc * 64 + j * 16 + cl;
      if (isQK) {
        if (gn < 1024) {
#pragma unroll
          for (int r = 0; r < 4; r++)
            Qb[(long)(gm + r) * 1024 + gn] = f2bf(acc[i][j][r]);
        } else {
#pragma unroll
          for (int r = 0; r < 4; r++)
            Kb[(long)(gm + r) * 1024 + (gn - 1024)] = f2bf(acc[i][j][r]);
        }
      } else {
#pragma unroll
        for (int r = 0; r < 4; r++)
          Wvo[(long)(gm + r) * 1024 + gn] = f2bf(acc[i][j][r]);
      }
    }
  }
}

// ---------------------------------------------------------------------------
// dispB: blocks [0,512) = VW GEMM (transposed store -> VWt);
//        blocks [512,1056) = S GEMM packed lower-triangular.
// 5 blocks/CU -> single occupancy round.
// ---------------------------------------------------------------------------
__global__ __launch_bounds__(256, 5)
void dispB(const unsigned short* __restrict__ Xbf, const unsigned short* __restrict__ Wvo,
           const unsigned short* __restrict__ Qb, const unsigned short* __restrict__ Kb,
           unsigned short* __restrict__ VWt, unsigned short* __restrict__ Sb)
{
  __shared__ short lds[2][BM * BK];
  const int flat = blockIdx.x;
  const bool isVW = flat < 512;
  int m0, n0, bz = 0;
  const unsigned short *Ab, *Bb;
  if (isVW) {
    const int swz = (flat & 7) * 64 + (flat >> 3);    // m204, nwg=512 (r=0)
    const int bx = swz & 7, by = swz >> 3;            // gx=8
    m0 = by * BM; n0 = bx * BN;
    Ab = Xbf + (long)m0 * 1024;
    Bb = Wvo + (long)n0 * 1024;
  } else {
    const int t = flat - 512;                         // 0..543
    bz = t / 136;
    const int tt = t - bz * 136;
    const int swz = (tt & 7) * 17 + (tt >> 3);        // m204, nwg=136 (17x8, r=0)
    int i = (int)((sqrtf(8.f * (float)swz + 1.f) - 1.f) * 0.5f);
    while ((i + 1) * (i + 2) / 2 <= swz) ++i;         // guard fp rounding
    while (i * (i + 1) / 2 > swz) --i;
    const int j = swz - i * (i + 1) / 2;
    m0 = i * BM; n0 = j * BN;
    Ab = Qb + ((long)bz * 2048 + m0) * 1024;
    Bb = Kb + ((long)bz * 2048 + n0) * 1024;
  }

  SB_PREAMBLE
  SB_KLOOP(Ab, Bb)

  const int rb4 = (lane >> 4) * 4;
  const int cl = lane & 15;
#pragma unroll
  for (int i = 0; i < 4; i++) {
#pragma unroll
    for (int j = 0; j < 4; j++) {
      const int gm = m0 + wr * 64 + i * 16 + rb4;
      const int gn = n0 + wc * 64 + j * 16 + cl;
      if (isVW) {
        // transposed store: VWt[b][d=gn][s], b = gm>>11, s = gm&2047
        const int b = gm >> 11;
        const int sIdx = gm & 2047;
        unsigned short* C = VWt + (long)b * (2048L * 1024) + (long)gn * 2048 + sIdx;
        ushort4 pk;
        pk.x = f2bf(acc[i][j][0]);
        pk.y = f2bf(acc[i][j][1]);
        pk.z = f2bf(acc[i][j][2]);
        pk.w = f2bf(acc[i][j][3]);
        *reinterpret_cast<ushort4*>(C) = pk;
      } else {
        unsigned short* C = Sb + (long)bz * (2048L * 2048);
#pragma unroll
        for (int r = 0; r < 4; r++)
          C[(long)(gm + r) * 2048 + gn] = f2bf(acc[i][j][r] * 0.03125f);
      }
    }
  }
}

// ---------------------------------------------------------------------------
// Double-buffered counted-vmcnt 128x128 GEMM-BT: PV -> out fp32+bias.
// Balanced causal pairing: z>=2 flips the m-tile so each CU's two co-resident
// blocks have complementary Keff (const 17x128 K-tiles per CU under
// round-robin assignment).
// ---------------------------------------------------------------------------
__global__ __launch_bounds__(256, 2)
void gemm_pv(const unsigned short* __restrict__ A, const unsigned short* __restrict__ B,
             float* __restrict__ Cv, const float* __restrict__ bias,
             int K, int ldA, int ldB, int ldC,
             long aBat, long bBat, long cBat)
{
  const int gx = gridDim.x;
  const int nwg = gx * gridDim.y;
  const int flat = blockIdx.y * gx + blockIdx.x;
  const int qch = nwg >> 3, rch = nwg & 7;
  const int xcd = flat & 7, idx = flat >> 3;
  const int swz = (xcd < rch ? xcd * (qch + 1) : rch * (qch + 1) + (xcd - rch) * qch) + idx;
  const int bx = swz % gx;
  const int bz = blockIdx.z;
  int by = swz / gx;
  if (bz >= 2) by = gridDim.y - 1 - by;      // complementary-Keff pairing

  const int m0 = by * BM;
  const int n0 = bx * BN;

  const unsigned short* Ab = A + (long)bz * aBat + (long)m0 * ldA;
  const unsigned short* Bb = B + (long)bz * bBat + (long)n0 * ldB;

  __shared__ short lds[2][2][BM * BK];

  const int tid = threadIdx.x;
  const int lane = tid & 63;
  const int wave = tid >> 6;
  const int wr = wave >> 1, wc = wave & 1;

  const int Keff = min(K, m0 + BM);          // causal K-limit
  const int nk = Keff / BK;

  const int srow = tid >> 3;
  const int sch = tid & 7;

  const f32x4 fzero = {0.f, 0.f, 0.f, 0.f};
  f32x4 acc[4][4];
#pragma unroll
  for (int i = 0; i < 4; i++)
#pragma unroll
    for (int j = 0; j < 4; j++) acc[i][j] = fzero;

  int aOff[4][2], bOff[4][2];
#pragma unroll
  for (int i = 0; i < 4; i++) {
#pragma unroll
    for (int s = 0; s < 2; s++) {
      int ra = wr * 64 + i * 16 + (lane & 15);
      aOff[i][s] = ra * BK + (((s * 4 + (lane >> 4)) ^ (ra & 7)) * 8);
      int rb = wc * 64 + i * 16 + (lane & 15);
      bOff[i][s] = rb * BK + (((s * 4 + (lane >> 4)) ^ (rb & 7)) * 8);
    }
  }

  auto stage = [&](int buf, int kt) {
    const unsigned short* Ak = Ab + kt * BK;
    const unsigned short* Bk = Bb + kt * BK;
#pragma unroll
    for (int r = 0; r < 4; r++) {
      int row = r * 32 + srow;
      int sc = sch ^ (row & 7);
      GLOAD16(Ak + (long)row * ldA + sc * 8, &lds[buf][0][(r * 32 + wave * 8) * BK]);
    }
#pragma unroll
    for (int r = 0; r < 4; r++) {
      int row = r * 32 + srow;
      int sc = sch ^ (row & 7);
      GLOAD16(Bk + (long)row * ldB + sc * 8, &lds[buf][1][(r * 32 + wave * 8) * BK]);
    }
  };

  stage(0, 0);
  stage(1, 1);
  asm volatile("s_waitcnt vmcnt(8)" ::: "memory");
  __builtin_amdgcn_sched_barrier(0);
  __builtin_amdgcn_s_barrier();

  int cur = 0;
  for (int kt = 0; kt < nk; kt++) {
    const short* La = lds[cur][0];
    const short* Lb = lds[cur][1];
    bf16x8 av[2][4], bv[2][4];
#pragma unroll
    for (int s = 0; s < 2; s++) {
#pragma unroll
      for (int i = 0; i < 4; i++) {
        av[s][i] = *reinterpret_cast<const bf16x8*>(La + aOff[i][s]);
        bv[s][i] = *reinterpret_cast<const bf16x8*>(Lb + bOff[i][s]);
      }
    }
    asm volatile("s_waitcnt lgkmcnt(0)" ::: "memory");
    __builtin_amdgcn_sched_barrier(0);
    __builtin_amdgcn_s_barrier();
    __builtin_amdgcn_sched_barrier(0);

    if (kt + 2 < nk) {
      stage(cur, kt + 2);
      asm volatile("s_waitcnt vmcnt(8)" ::: "memory");
    } else if (kt + 1 < nk) {
      asm volatile("s_waitcnt vmcnt(0)" ::: "memory");
    }
    if (kt + 1 < nk) {
      __builtin_amdgcn_s_barrier();
      __builtin_amdgcn_sched_barrier(0);
    }

    __builtin_amdgcn_s_setprio(1);
#pragma unroll
    for (int s = 0; s < 2; s++)
#pragma unroll
      for (int i = 0; i < 4; i++)
#pragma unroll
        for (int j = 0; j < 4; j++)
          acc[i][j] = __builtin_amdgcn_mfma_f32_16x16x32_bf16(av[s][i], bv[s][j], acc[i][j], 0, 0, 0);
    __builtin_amdgcn_s_setprio(0);
    __builtin_amdgcn_sched_barrier(0);
    cur ^= 1;
  }

  const int rb4 = (lane >> 4) * 4;
  const int cl = lane & 15;
#pragma unroll
  for (int i = 0; i < 4; i++) {
#pragma unroll
    for (int j = 0; j < 4; j++) {
      const int gm = m0 + wr * 64 + i * 16 + rb4;
      const int gn = n0 + wc * 64 + j * 16 + cl;
      float* C = Cv + (long)bz * cBat;
      const float bb = bias[gn];
#pragma unroll
      for (int r = 0; r < 4; r++)
        C[(long)(gm + r) * ldC + gn] = acc[i][j][r] + bb;
    }
  }
}

// one WAVE per (q row); 4 rows per block; shfl-only reduction.
__global__ __launch_bounds__(256)
void softmax_rows(const unsigned short* __restrict__ Sb, const float* __restrict__ maskv,
                  unsigned short* __restrict__ P, int Sdim)
{
  const int wv = threadIdx.x >> 6;
  const int lane = threadIdx.x & 63;
  const int q = blockIdx.x * 4 + wv;
  const int b = blockIdx.y;
  const int kmax = (q & ~127) + 128;
  const unsigned short* row = Sb + ((long)b * Sdim + q) * Sdim;
  unsigned short* prow = P + ((long)b * Sdim + q) * Sdim;
  const float* mrow = maskv + (long)b * Sdim;
  const float mq = mrow[q];

  float v[4][8];
  float mx = -INFINITY;
#pragma unroll
  for (int c = 0; c < 4; c++) {
    const int k0 = c * 512 + lane * 8;
    if (c * 512 < kmax) {
      uint4 raw = *reinterpret_cast<const uint4*>(row + k0);
      const unsigned short* us = reinterpret_cast<const unsigned short*>(&raw);
      float4 ma = *reinterpret_cast<const float4*>(mrow + k0);
      float4 mb = *reinterpret_cast<const float4*>(mrow + k0 + 4);
      float mv[8] = {ma.x, ma.y, ma.z, ma.w, mb.x, mb.y, mb.z, mb.w};
#pragma unroll
      for (int u = 0; u < 8; u++) {
        const int k = k0 + u;
        const bool ok = (k <= q) && (mq * mv[u] == 1.0f);   // square_mask == 1 semantics
        v[c][u] = ok ? bf2f(us[u]) : -INFINITY;
        mx = fmaxf(mx, v[c][u]);
      }
    } else {
#pragma unroll
      for (int u = 0; u < 8; u++) v[c][u] = -INFINITY;
    }
  }
#pragma unroll
  for (int o = 32; o; o >>= 1) mx = fmaxf(mx, __shfl_xor(mx, o));

  float sm = 0.f;
#pragma unroll
  for (int c = 0; c < 4; c++)
#pragma unroll
    for (int u = 0; u < 8; u++) {
      v[c][u] = (v[c][u] > -INFINITY) ? __expf(v[c][u] - mx) : 0.f;
      sm += v[c][u];
    }
#pragma unroll
  for (int o = 32; o; o >>= 1) sm += __shfl_xor(sm, o);
  const float inv = 1.0f / sm;

#pragma unroll
  for (int c = 0; c < 4; c++) {
    if (c * 512 < kmax) {
      union { unsigned short us[8]; uint4 u4; } pk;
#pragma unroll
      for (int u = 0; u < 8; u++) pk.us[u] = f2bf(v[c][u] * inv);
      *reinterpret_cast<uint4*>(prow + c * 512 + lane * 8) = pk.u4;
    }
  }
}

// ---------------------------------------------------------------------------
// cast_all2 — ALL casts in one dispatch:
// [0,4096) x; [4096,4608) Wq; [4608,5120) Wk; [5120,5632) Wo; [5632,5888) Wv^T
// ---------------------------------------------------------------------------
__global__ __launch_bounds__(256)
void cast_all2(const float* __restrict__ x, const float* __restrict__ Wq,
               const float* __restrict__ Wk, const float* __restrict__ Wv,
               const float* __restrict__ Wo,
               unsigned short* __restrict__ xb, unsigned short* __restrict__ Wqk,
               unsigned short* __restrict__ Wob, unsigned short* __restrict__ Wvt)
{
  __shared__ float t[64][65];
  const int blk = blockIdx.x;
  const int tid = threadIdx.x;
  if (blk < 5632) {
    const float* src;
    unsigned short* dst;
    int i;
    if (blk < 4096) {
      src = x; dst = xb; i = (blk * 256 + tid) * 8;
    } else {
      const int w = (blk - 4096) >> 9;          // 0,1,2
      const int off = (blk - 4096) & 511;
      src = (w == 0) ? Wq : (w == 1) ? Wk : Wo;
      dst = (w == 0) ? Wqk : (w == 1) ? (Wqk + 1024L * 1024) : Wob;
      i = (off * 256 + tid) * 8;
    }
    float4 a = *reinterpret_cast<const float4*>(src + i);
    float4 b = *reinterpret_cast<const float4*>(src + i + 4);
    union { unsigned short us[8]; uint4 u4; } pk;
    pk.us[0] = f2bf(a.x); pk.us[1] = f2bf(a.y); pk.us[2] = f2bf(a.z); pk.us[3] = f2bf(a.w);
    pk.us[4] = f2bf(b.x); pk.us[5] = f2bf(b.y); pk.us[6] = f2bf(b.z); pk.us[7] = f2bf(b.w);
    *reinterpret_cast<uint4*>(dst + i) = pk.u4;
    return;
  }
  // Wv transpose-cast: 64x64 tile per block
  const int tile = blk - 5632;                 // 0..255
  const int a0 = (tile >> 4) * 64;
  const int m0 = (tile & 15) * 64;
#pragma unroll
  for (int i = 0; i < 4; i++) {
    const int row = (tid >> 4) + i * 16;
    const int col4 = tid & 15;
    float4 f4 = *reinterpret_cast<const float4*>(Wv + (long)(a0 + row) * 1024 + m0 + col4 * 4);
    t[row][col4 * 4 + 0] = f4.x;
    t[row][col4 * 4 + 1] = f4.y;
    t[row][col4 * 4 + 2] = f4.z;
    t[row][col4 * 4 + 3] = f4.w;
  }
  __syncthreads();
#pragma unroll
  for (int j = 0; j < 2; j++) {
    const int mm = (tid >> 3) + j * 32;
    const int aa0 = (tid & 7) * 8;
    union { unsigned short us[8]; uint4 u4; } pk;
#pragma unroll
    for (int u = 0; u < 8; u++) pk.us[u] = f2bf(t[aa0 + u][mm]);
    *reinterpret_cast<uint4*>(Wvt + (long)(m0 + mm) * 1024 + a0 + aa0) = pk.u4;
  }
}

extern "C" void kernel_launch(void* const* d_in, const int* in_sizes, int n_in,
                              void* d_out, int out_size, void* d_ws, size_t ws_size,
                              hipStream_t stream)
{
  const int B = 4, S = 2048, D = 1024;
  const float* x  = (const float*)d_in[0];
  const float* mk = (const float*)d_in[1];
  const float* Wq = (const float*)d_in[2];
  const float* Wk = (const float*)d_in[3];
  const float* Wv = (const float*)d_in[4];
  const float* Wo = (const float*)d_in[5];
  const float* bo = (const float*)d_in[6];
  float* out = (float*)d_out;

  char* ws = (char*)d_ws;
  const long MB = 1024L * 1024L;
  unsigned short* Xbf  = (unsigned short*)(ws + 0);        // 16MB (live through dispB)
  unsigned short* Qb   = (unsigned short*)(ws + 16 * MB);  // 16MB [8192][1024]; -> P
  unsigned short* Kb   = (unsigned short*)(ws + 32 * MB);  // 16MB [8192][1024]; -> P
  unsigned short* VWt  = (unsigned short*)(ws + 48 * MB);  // 16MB VW^T per batch [D][S]
  unsigned short* Wqk  = (unsigned short*)(ws + 64 * MB);  // 4MB [2048][1024] Wq|Wk
  unsigned short* Wvo  = (unsigned short*)(ws + 68 * MB);  // 2MB [1024][1024]
  unsigned short* Wob  = (unsigned short*)(ws + 70 * MB);  // 2MB
  unsigned short* Sbuf = (unsigned short*)(ws + 72 * MB);  // 32MB bf16 logits
  unsigned short* Wvt  = Sbuf;                             // 2MB overlay (dead before S writes)
  unsigned short* P    = Qb;                               // 32MB over dead Q+K

  if (ws_size < (size_t)(104 * MB)) {
    fprintf(stderr, "kernel_launch: ws too small (%zu bytes, need 104MB)\n", ws_size);
    return;
  }

  // 1) all casts (x, Wq, Wk, Wo, Wv^T) in one dispatch
  cast_all2<<<dim3(5888), dim3(256), 0, stream>>>(x, Wq, Wk, Wv, Wo, Xbf, Wqk, Wob, Wvt);
  // 2) dispA: QK projection (1024 blocks) || Wvo = Wo*Wv (64 blocks) — one round @5/CU
  dispA<<<dim3(1088), dim3(256), 0, stream>>>(Xbf, Wqk, Wob, Wvt, Qb, Kb, Wvo);
  // 3) dispB: VW (512) || S triangular (544) — one round @5/CU
  dispB<<<dim3(1056), dim3(256), 0, stream>>>(Xbf, Wvo, Qb, Kb, VWt, Sbuf);
  // 4) softmax -> P bf16
  softmax_rows<<<dim3(512, 4), dim3(256), 0, stream>>>(Sbuf, mk, P, 2048);
  // 5) out = P * VWt^T + bo (fp32 direct, causal K-limit, balanced pairing)
  dim3 gO(1024 / BN, 2048 / BM, 4);
  gemm_pv<<<gO, dim3(256), 0, stream>>>(P, VWt, out, bo,
                                        2048, 2048, 2048, 1024,
                                        (long)S * S, (long)D * S, (long)S * D);
}

// Round 11
// 155.734 us; speedup vs baseline: 1.3799x; 1.0174x over previous
//
#include <hip/hip_runtime.h>
#include <hip/hip_bf16.h>
#include <cstdio>

typedef __bf16 bf16x8 __attribute__((ext_vector_type(8)));
typedef float f32x4 __attribute__((ext_vector_type(4)));

#define BM 128
#define BN 128
#define BK 64

__device__ __forceinline__ unsigned short f2bf(float f) {
  union { float f; unsigned u; } v; v.f = f;
  unsigned u = v.u;
  return (unsigned short)((u + 0x7FFFu + ((u >> 16) & 1u)) >> 16);
}

__device__ __forceinline__ float bf2f(unsigned short s) {
  union { unsigned u; float f; } v; v.u = ((unsigned)s) << 16;
  return v.f;
}

#define GLOAD16(gsrc, ldst) \
  __builtin_amdgcn_global_load_lds((const __attribute__((address_space(1))) void*)(gsrc), \
                                   (__attribute__((address_space(3))) void*)(ldst), 16, 0, 0)

// ---------------------------------------------------------------------------
// Shared single-buffered K-loop body (m97-style, verified): ld == 1024, nk=16.
// ---------------------------------------------------------------------------
#define SB_KLOOP(Ab, Bb)                                                        \
  for (int kt = 0; kt < 16; kt++) {                                             \
    const unsigned short* Ak = (Ab) + kt * BK;                                  \
    const unsigned short* Bk = (Bb) + kt * BK;                                  \
    _Pragma("unroll")                                                           \
    for (int r = 0; r < 4; r++) {                                               \
      int row = r * 32 + srow;                                                  \
      int sc = sch ^ (row & 7);                                                 \
      GLOAD16(Ak + (long)row * 1024 + sc * 8, &lds[0][(r * 32 + wave * 8) * BK]);\
    }                                                                           \
    _Pragma("unroll")                                                           \
    for (int r = 0; r < 4; r++) {                                               \
      int row = r * 32 + srow;                                                  \
      int sc = sch ^ (row & 7);                                                 \
      GLOAD16(Bk + (long)row * 1024 + sc * 8, &lds[1][(r * 32 + wave * 8) * BK]);\
    }                                                                           \
    __syncthreads();                                                            \
    _Pragma("unroll")                                                           \
    for (int s = 0; s < 2; s++) {                                               \
      bf16x8 av[4], bv[4];                                                      \
      _Pragma("unroll")                                                         \
      for (int i = 0; i < 4; i++) av[i] = *reinterpret_cast<const bf16x8*>(lds[0] + aOff[i][s]); \
      _Pragma("unroll")                                                         \
      for (int j = 0; j < 4; j++) bv[j] = *reinterpret_cast<const bf16x8*>(lds[1] + bOff[j][s]); \
      _Pragma("unroll")                                                         \
      for (int i = 0; i < 4; i++)                                               \
        _Pragma("unroll")                                                       \
        for (int j = 0; j < 4; j++)                                             \
          acc[i][j] = __builtin_amdgcn_mfma_f32_16x16x32_bf16(av[i], bv[j], acc[i][j], 0, 0, 0); \
    }                                                                           \
    __syncthreads();                                                            \
  }

#define SB_PREAMBLE                                                             \
  const int tid = threadIdx.x;                                                  \
  const int lane = tid & 63;                                                    \
  const int wave = tid >> 6;                                                    \
  const int wr = wave >> 1, wc = wave & 1;                                      \
  const int srow = tid >> 3;                                                    \
  const int sch = tid & 7;                                                      \
  const f32x4 fzero = {0.f, 0.f, 0.f, 0.f};                                     \
  f32x4 acc[4][4];                                                              \
  _Pragma("unroll")                                                             \
  for (int i = 0; i < 4; i++)                                                   \
    _Pragma("unroll")                                                           \
    for (int j = 0; j < 4; j++) acc[i][j] = fzero;                              \
  int aOff[4][2], bOff[4][2];                                                   \
  _Pragma("unroll")                                                             \
  for (int i = 0; i < 4; i++) {                                                 \
    _Pragma("unroll")                                                           \
    for (int s = 0; s < 2; s++) {                                               \
      int ra = wr * 64 + i * 16 + (lane & 15);                                  \
      aOff[i][s] = ra * BK + (((s * 4 + (lane >> 4)) ^ (ra & 7)) * 8);          \
      int rb = wc * 64 + i * 16 + (lane & 15);                                  \
      bOff[i][s] = rb * BK + (((s * 4 + (lane >> 4)) ^ (rb & 7)) * 8);          \
    }                                                                           \
  }

// ---------------------------------------------------------------------------
// cast_w: [0,512) Wq -> Wqk[0:1024); [512,1024) Wk -> Wqk[1024:2048);
// [1024,1536) Wo -> Wob; [1536,1792) Wv transpose-cast -> Wvt[m][a]=Wv[a][m].
// ---------------------------------------------------------------------------
__global__ __launch_bounds__(256)
void cast_w(const float* __restrict__ Wq, const float* __restrict__ Wk,
            const float* __restrict__ Wv, const float* __restrict__ Wo,
            unsigned short* __restrict__ Wqk, unsigned short* __restrict__ Wob,
            unsigned short* __restrict__ Wvt)
{
  const int blk = blockIdx.x;
  const int tid = threadIdx.x;
  if (blk < 1536) {
    const int w = blk >> 9;                    // 0,1,2
    const int off = blk & 511;
    const float* src = (w == 0) ? Wq : (w == 1) ? Wk : Wo;
    unsigned short* dst = (w == 0) ? Wqk : (w == 1) ? (Wqk + 1024L * 1024) : Wob;
    const int i = (off * 256 + tid) * 8;
    float4 a = *reinterpret_cast<const float4*>(src + i);
    float4 b = *reinterpret_cast<const float4*>(src + i + 4);
    union { unsigned short us[8]; uint4 u4; } pk;
    pk.us[0] = f2bf(a.x); pk.us[1] = f2bf(a.y); pk.us[2] = f2bf(a.z); pk.us[3] = f2bf(a.w);
    pk.us[4] = f2bf(b.x); pk.us[5] = f2bf(b.y); pk.us[6] = f2bf(b.z); pk.us[7] = f2bf(b.w);
    *reinterpret_cast<uint4*>(dst + i) = pk.u4;
    return;
  }
  __shared__ float t[64][65];
  const int tile = blk - 1536;                 // 0..255
  const int a0 = (tile >> 4) * 64;
  const int m0 = (tile & 15) * 64;
#pragma unroll
  for (int i = 0; i < 4; i++) {
    const int row = (tid >> 4) + i * 16;
    const int col4 = tid & 15;
    float4 f4 = *reinterpret_cast<const float4*>(Wv + (long)(a0 + row) * 1024 + m0 + col4 * 4);
    t[row][col4 * 4 + 0] = f4.x;
    t[row][col4 * 4 + 1] = f4.y;
    t[row][col4 * 4 + 2] = f4.z;
    t[row][col4 * 4 + 3] = f4.w;
  }
  __syncthreads();
#pragma unroll
  for (int j = 0; j < 2; j++) {
    const int mm = (tid >> 3) + j * 32;
    const int aa0 = (tid & 7) * 8;
    union { unsigned short us[8]; uint4 u4; } pk;
#pragma unroll
    for (int u = 0; u < 8; u++) pk.us[u] = f2bf(t[aa0 + u][mm]);
    *reinterpret_cast<uint4*>(Wvt + (long)(m0 + mm) * 1024 + a0 + aa0) = pk.u4;
  }
}

// ---------------------------------------------------------------------------
// prep2: blocks [0,64) = Wvo = Wo*Wv GEMM (8x8 grid, sb body);
//        blocks [64,4160) = x-cast. Wvo hides under the HBM-bound cast.
// ---------------------------------------------------------------------------
__global__ __launch_bounds__(256, 3)
void prep2(const float* __restrict__ x, unsigned short* __restrict__ xb,
           const unsigned short* __restrict__ Wob, const unsigned short* __restrict__ Wvt,
           unsigned short* __restrict__ Wvo)
{
  __shared__ short lds[2][BM * BK];
  if (blockIdx.x >= 64) {
    const int blk = blockIdx.x - 64;
    const int i = (blk * 256 + (int)threadIdx.x) * 8;
    float4 a = *reinterpret_cast<const float4*>(x + i);
    float4 b = *reinterpret_cast<const float4*>(x + i + 4);
    union { unsigned short us[8]; uint4 u4; } pk;
    pk.us[0] = f2bf(a.x); pk.us[1] = f2bf(a.y); pk.us[2] = f2bf(a.z); pk.us[3] = f2bf(a.w);
    pk.us[4] = f2bf(b.x); pk.us[5] = f2bf(b.y); pk.us[6] = f2bf(b.z); pk.us[7] = f2bf(b.w);
    *reinterpret_cast<uint4*>(xb + i) = pk.u4;
    return;
  }
  const int t = blockIdx.x;                    // 0..63
  const int m0 = (t >> 3) * BM, n0 = (t & 7) * BN;
  const unsigned short* Ab = Wob + (long)m0 * 1024;
  const unsigned short* Bb = Wvt + (long)n0 * 1024;

  SB_PREAMBLE
  SB_KLOOP(Ab, Bb)

  const int rb4 = (lane >> 4) * 4;
  const int cl = lane & 15;
#pragma unroll
  for (int i = 0; i < 4; i++) {
#pragma unroll
    for (int j = 0; j < 4; j++) {
      const int gm = m0 + wr * 64 + i * 16 + rb4;
      const int gn = n0 + wc * 64 + j * 16 + cl;
#pragma unroll
      for (int r = 0; r < 4; r++)
        Wvo[(long)(gm + r) * 1024 + gn] = f2bf(acc[i][j][r]);
    }
  }
}

// ---------------------------------------------------------------------------
// dispA2: blocks [0,1024) = QK projection (M=8192, N=2048);
//         blocks [1024,1536) = VW = X*Wvo^T (transposed store -> VWt).
// 1536 blocks = exactly 2 rounds @3/CU.
// ---------------------------------------------------------------------------
__global__ __launch_bounds__(256, 3)
void dispA2(const unsigned short* __restrict__ Xbf, const unsigned short* __restrict__ Wqk,
            const unsigned short* __restrict__ Wvo,
            unsigned short* __restrict__ Qb, unsigned short* __restrict__ Kb,
            unsigned short* __restrict__ VWt)
{
  __shared__ short lds[2][BM * BK];
  const int flat = blockIdx.x;
  const bool isQK = flat < 1024;
  int m0, n0;
  const unsigned short *Ab, *Bb;
  if (isQK) {
    const int swz = (flat & 7) * 128 + (flat >> 3);   // m204, nwg=1024 (r=0)
    const int bx = swz & 15, by = swz >> 4;           // gx=16
    m0 = by * BM; n0 = bx * BN;
    Ab = Xbf + (long)m0 * 1024;
    Bb = Wqk + (long)n0 * 1024;
  } else {
    const int t = flat - 1024;                        // 0..511
    const int swz = (t & 7) * 64 + (t >> 3);          // m204, nwg=512 (r=0)
    const int bx = swz & 7, by = swz >> 3;            // gx=8
    m0 = by * BM; n0 = bx * BN;
    Ab = Xbf + (long)m0 * 1024;
    Bb = Wvo + (long)n0 * 1024;
  }

  SB_PREAMBLE
  SB_KLOOP(Ab, Bb)

  const int rb4 = (lane >> 4) * 4;
  const int cl = lane & 15;
#pragma unroll
  for (int i = 0; i < 4; i++) {
#pragma unroll
    for (int j = 0; j < 4; j++) {
      const int gm = m0 + wr * 64 + i * 16 + rb4;
      const int gn = n0 + wc * 64 + j * 16 + cl;
      if (isQK) {
        if (gn < 1024) {
#pragma unroll
          for (int r = 0; r < 4; r++)
            Qb[(long)(gm + r) * 1024 + gn] = f2bf(acc[i][j][r]);
        } else {
#pragma unroll
          for (int r = 0; r < 4; r++)
            Kb[(long)(gm + r) * 1024 + (gn - 1024)] = f2bf(acc[i][j][r]);
        }
      } else {
        // transposed store: VWt[b][d=gn][s], b = gm>>11, s = gm&2047
        const int b = gm >> 11;
        const int sIdx = gm & 2047;
        unsigned short* C = VWt + (long)b * (2048L * 1024) + (long)gn * 2048 + sIdx;
        ushort4 pk;
        pk.x = f2bf(acc[i][j][0]);
        pk.y = f2bf(acc[i][j][1]);
        pk.z = f2bf(acc[i][j][2]);
        pk.w = f2bf(acc[i][j][3]);
        *reinterpret_cast<ushort4*>(C) = pk;
      }
    }
  }
}

// ---------------------------------------------------------------------------
// dispS: S = Q K^T / 32, packed lower-triangular (136 tiles x 4 batches).
// ---------------------------------------------------------------------------
__global__ __launch_bounds__(256, 3)
void dispS(const unsigned short* __restrict__ Qb, const unsigned short* __restrict__ Kb,
           unsigned short* __restrict__ Sb)
{
  __shared__ short lds[2][BM * BK];
  const int t = blockIdx.x;                           // 0..543
  const int bz = t / 136;
  const int tt = t - bz * 136;
  const int swz = (tt & 7) * 17 + (tt >> 3);          // m204, nwg=136 (17x8, r=0)
  int i = (int)((sqrtf(8.f * (float)swz + 1.f) - 1.f) * 0.5f);
  while ((i + 1) * (i + 2) / 2 <= swz) ++i;
  while (i * (i + 1) / 2 > swz) --i;
  const int j = swz - i * (i + 1) / 2;
  const int m0 = i * BM, n0 = j * BN;
  const unsigned short* Ab = Qb + ((long)bz * 2048 + m0) * 1024;
  const unsigned short* Bb = Kb + ((long)bz * 2048 + n0) * 1024;

  SB_PREAMBLE
  SB_KLOOP(Ab, Bb)

  const int rb4 = (lane >> 4) * 4;
  const int cl = lane & 15;
  unsigned short* C = Sb + (long)bz * (2048L * 2048);
#pragma unroll
  for (int ii = 0; ii < 4; ii++) {
#pragma unroll
    for (int jj = 0; jj < 4; jj++) {
      const int gm = m0 + wr * 64 + ii * 16 + rb4;
      const int gn = n0 + wc * 64 + jj * 16 + cl;
#pragma unroll
      for (int r = 0; r < 4; r++)
        C[(long)(gm + r) * 2048 + gn] = f2bf(acc[ii][jj][r] * 0.03125f);
    }
  }
}

// ---------------------------------------------------------------------------
// Double-buffered counted-vmcnt 128x128 GEMM-BT: PV -> out fp32+bias.
// Balanced causal pairing (z>=2 flips m).
// ---------------------------------------------------------------------------
__global__ __launch_bounds__(256, 2)
void gemm_pv(const unsigned short* __restrict__ A, const unsigned short* __restrict__ B,
             float* __restrict__ Cv, const float* __restrict__ bias,
             int K, int ldA, int ldB, int ldC,
             long aBat, long bBat, long cBat)
{
  const int gx = gridDim.x;
  const int nwg = gx * gridDim.y;
  const int flat = blockIdx.y * gx + blockIdx.x;
  const int qch = nwg >> 3, rch = nwg & 7;
  const int xcd = flat & 7, idx = flat >> 3;
  const int swz = (xcd < rch ? xcd * (qch + 1) : rch * (qch + 1) + (xcd - rch) * qch) + idx;
  const int bx = swz % gx;
  const int bz = blockIdx.z;
  int by = swz / gx;
  if (bz >= 2) by = gridDim.y - 1 - by;      // complementary-Keff pairing

  const int m0 = by * BM;
  const int n0 = bx * BN;

  const unsigned short* Ab = A + (long)bz * aBat + (long)m0 * ldA;
  const unsigned short* Bb = B + (long)bz * bBat + (long)n0 * ldB;

  __shared__ short lds[2][2][BM * BK];

  const int tid = threadIdx.x;
  const int lane = tid & 63;
  const int wave = tid >> 6;
  const int wr = wave >> 1, wc = wave & 1;

  const int Keff = min(K, m0 + BM);          // causal K-limit
  const int nk = Keff / BK;

  const int srow = tid >> 3;
  const int sch = tid & 7;

  const f32x4 fzero = {0.f, 0.f, 0.f, 0.f};
  f32x4 acc[4][4];
#pragma unroll
  for (int i = 0; i < 4; i++)
#pragma unroll
    for (int j = 0; j < 4; j++) acc[i][j] = fzero;

  int aOff[4][2], bOff[4][2];
#pragma unroll
  for (int i = 0; i < 4; i++) {
#pragma unroll
    for (int s = 0; s < 2; s++) {
      int ra = wr * 64 + i * 16 + (lane & 15);
      aOff[i][s] = ra * BK + (((s * 4 + (lane >> 4)) ^ (ra & 7)) * 8);
      int rb = wc * 64 + i * 16 + (lane & 15);
      bOff[i][s] = rb * BK + (((s * 4 + (lane >> 4)) ^ (rb & 7)) * 8);
    }
  }

  auto stage = [&](int buf, int kt) {
    const unsigned short* Ak = Ab + kt * BK;
    const unsigned short* Bk = Bb + kt * BK;
#pragma unroll
    for (int r = 0; r < 4; r++) {
      int row = r * 32 + srow;
      int sc = sch ^ (row & 7);
      GLOAD16(Ak + (long)row * ldA + sc * 8, &lds[buf][0][(r * 32 + wave * 8) * BK]);
    }
#pragma unroll
    for (int r = 0; r < 4; r++) {
      int row = r * 32 + srow;
      int sc = sch ^ (row & 7);
      GLOAD16(Bk + (long)row * ldB + sc * 8, &lds[buf][1][(r * 32 + wave * 8) * BK]);
    }
  };

  stage(0, 0);
  stage(1, 1);
  asm volatile("s_waitcnt vmcnt(8)" ::: "memory");
  __builtin_amdgcn_sched_barrier(0);
  __builtin_amdgcn_s_barrier();

  int cur = 0;
  for (int kt = 0; kt < nk; kt++) {
    const short* La = lds[cur][0];
    const short* Lb = lds[cur][1];
    bf16x8 av[2][4], bv[2][4];
#pragma unroll
    for (int s = 0; s < 2; s++) {
#pragma unroll
      for (int i = 0; i < 4; i++) {
        av[s][i] = *reinterpret_cast<const bf16x8*>(La + aOff[i][s]);
        bv[s][i] = *reinterpret_cast<const bf16x8*>(Lb + bOff[i][s]);
      }
    }
    asm volatile("s_waitcnt lgkmcnt(0)" ::: "memory");
    __builtin_amdgcn_sched_barrier(0);
    __builtin_amdgcn_s_barrier();
    __builtin_amdgcn_sched_barrier(0);

    if (kt + 2 < nk) {
      stage(cur, kt + 2);
      asm volatile("s_waitcnt vmcnt(8)" ::: "memory");
    } else if (kt + 1 < nk) {
      asm volatile("s_waitcnt vmcnt(0)" ::: "memory");
    }
    if (kt + 1 < nk) {
      __builtin_amdgcn_s_barrier();
      __builtin_amdgcn_sched_barrier(0);
    }

    __builtin_amdgcn_s_setprio(1);
#pragma unroll
    for (int s = 0; s < 2; s++)
#pragma unroll
      for (int i = 0; i < 4; i++)
#pragma unroll
        for (int j = 0; j < 4; j++)
          acc[i][j] = __builtin_amdgcn_mfma_f32_16x16x32_bf16(av[s][i], bv[s][j], acc[i][j], 0, 0, 0);
    __builtin_amdgcn_s_setprio(0);
    __builtin_amdgcn_sched_barrier(0);
    cur ^= 1;
  }

  const int rb4 = (lane >> 4) * 4;
  const int cl = lane & 15;
#pragma unroll
  for (int i = 0; i < 4; i++) {
#pragma unroll
    for (int j = 0; j < 4; j++) {
      const int gm = m0 + wr * 64 + i * 16 + rb4;
      const int gn = n0 + wc * 64 + j * 16 + cl;
      float* C = Cv + (long)bz * cBat;
      const float bb = bias[gn];
#pragma unroll
      for (int r = 0; r < 4; r++)
        C[(long)(gm + r) * ldC + gn] = acc[i][j][r] + bb;
    }
  }
}

// one WAVE per (q row); 4 rows per block; shfl-only reduction.
__global__ __launch_bounds__(256)
void softmax_rows(const unsigned short* __restrict__ Sb, const float* __restrict__ maskv,
                  unsigned short* __restrict__ P, int Sdim)
{
  const int wv = threadIdx.x >> 6;
  const int lane = threadIdx.x & 63;
  const int q = blockIdx.x * 4 + wv;
  const int b = blockIdx.y;
  const int kmax = (q & ~127) + 128;
  const unsigned short* row = Sb + ((long)b * Sdim + q) * Sdim;
  unsigned short* prow = P + ((long)b * Sdim + q) * Sdim;
  const float* mrow = maskv + (long)b * Sdim;
  const float mq = mrow[q];

  float v[4][8];
  float mx = -INFINITY;
#pragma unroll
  for (int c = 0; c < 4; c++) {
    const int k0 = c * 512 + lane * 8;
    if (c * 512 < kmax) {
      uint4 raw = *reinterpret_cast<const uint4*>(row + k0);
      const unsigned short* us = reinterpret_cast<const unsigned short*>(&raw);
      float4 ma = *reinterpret_cast<const float4*>(mrow + k0);
      float4 mb = *reinterpret_cast<const float4*>(mrow + k0 + 4);
      float mv[8] = {ma.x, ma.y, ma.z, ma.w, mb.x, mb.y, mb.z, mb.w};
#pragma unroll
      for (int u = 0; u < 8; u++) {
        const int k = k0 + u;
        const bool ok = (k <= q) && (mq * mv[u] == 1.0f);   // square_mask == 1 semantics
        v[c][u] = ok ? bf2f(us[u]) : -INFINITY;
        mx = fmaxf(mx, v[c][u]);
      }
    } else {
#pragma unroll
      for (int u = 0; u < 8; u++) v[c][u] = -INFINITY;
    }
  }
#pragma unroll
  for (int o = 32; o; o >>= 1) mx = fmaxf(mx, __shfl_xor(mx, o));

  float sm = 0.f;
#pragma unroll
  for (int c = 0; c < 4; c++)
#pragma unroll
    for (int u = 0; u < 8; u++) {
      v[c][u] = (v[c][u] > -INFINITY) ? __expf(v[c][u] - mx) : 0.f;
      sm += v[c][u];
    }
#pragma unroll
  for (int o = 32; o; o >>= 1) sm += __shfl_xor(sm, o);
  const float inv = 1.0f / sm;

#pragma unroll
  for (int c = 0; c < 4; c++) {
    if (c * 512 < kmax) {
      union { unsigned short us[8]; uint4 u4; } pk;
#pragma unroll
      for (int u = 0; u < 8; u++) pk.us[u] = f2bf(v[c][u] * inv);
      *reinterpret_cast<uint4*>(prow + c * 512 + lane * 8) = pk.u4;
    }
  }
}

extern "C" void kernel_launch(void* const* d_in, const int* in_sizes, int n_in,
                              void* d_out, int out_size, void* d_ws, size_t ws_size,
                              hipStream_t stream)
{
  const int B = 4, S = 2048, D = 1024;
  const float* x  = (const float*)d_in[0];
  const float* mk = (const float*)d_in[1];
  const float* Wq = (const float*)d_in[2];
  const float* Wk = (const float*)d_in[3];
  const float* Wv = (const float*)d_in[4];
  const float* Wo = (const float*)d_in[5];
  const float* bo = (const float*)d_in[6];
  float* out = (float*)d_out;

  char* ws = (char*)d_ws;
  const long MB = 1024L * 1024L;
  unsigned short* Xbf  = (unsigned short*)(ws + 0);        // 16MB (live through dispA2)
  unsigned short* Qb   = (unsigned short*)(ws + 16 * MB);  // 16MB [8192][1024]; -> P
  unsigned short* Kb   = (unsigned short*)(ws + 32 * MB);  // 16MB [8192][1024]; -> P
  unsigned short* VWt  = (unsigned short*)(ws + 48 * MB);  // 16MB VW^T per batch [D][S]
  unsigned short* Wqk  = (unsigned short*)(ws + 64 * MB);  // 4MB [2048][1024] Wq|Wk
  unsigned short* Wvo  = (unsigned short*)(ws + 68 * MB);  // 2MB [1024][1024]
  unsigned short* Wob  = (unsigned short*)(ws + 70 * MB);  // 2MB
  unsigned short* Sbuf = (unsigned short*)(ws + 72 * MB);  // 32MB bf16 logits
  unsigned short* Wvt  = Sbuf;                             // 2MB overlay (dead before S writes)
  unsigned short* P    = Qb;                               // 32MB over dead Q+K

  if (ws_size < (size_t)(104 * MB)) {
    fprintf(stderr, "kernel_launch: ws too small (%zu bytes, need 104MB)\n", ws_size);
    return;
  }

  // 1) weight casts (Wq, Wk, Wo, Wv^T)
  cast_w<<<dim3(1792), dim3(256), 0, stream>>>(Wq, Wk, Wv, Wo, Wqk, Wob, Wvt);
  // 2) Wvo = Wo*Wv (64 blocks) hidden under x-cast (4096 blocks)
  prep2<<<dim3(4160), dim3(256), 0, stream>>>(x, Xbf, Wob, Wvt, Wvo);
  // 3) QK projection (1024) || VW = X*Wvo^T (512) — 2 clean rounds @3/CU
  dispA2<<<dim3(1536), dim3(256), 0, stream>>>(Xbf, Wqk, Wvo, Qb, Kb, VWt);
  // 4) S = Q K^T / 32, packed triangular (544 blocks, one round)
  dispS<<<dim3(544), dim3(256), 0, stream>>>(Qb, Kb, Sbuf);
  // 5) softmax -> P bf16
  softmax_rows<<<dim3(512, 4), dim3(256), 0, stream>>>(Sbuf, mk, P, 2048);
  // 6) out = P * VWt^T + bo (fp32 direct, causal K-limit, balanced pairing)
  dim3 gO(1024 / BN, 2048 / BM, 4);
  gemm_pv<<<gO, dim3(256), 0, stream>>>(P, VWt, out, bo,
                                        2048, 2048, 2048, 1024,
                                        (long)S * S, (long)D * S, (long)S * D);
}